// Round 17
// baseline (845.324 us; speedup 1.0000x reference)
//
#include <hip/hip_runtime.h>

// RWKV7-delta time-mix. f32 in/out, bf16 intermediates + MFMA bf16 16x16x32.
// B=2 T=4096 C=2048 H=32 K=64 CHUNK=128 NC=32.

typedef unsigned short u16;
typedef unsigned int   u32;
typedef __attribute__((ext_vector_type(8))) short s16x8;
typedef __attribute__((ext_vector_type(4))) float f32x4;

#define DEV __device__ __forceinline__

DEV float b2f(u16 v){ return __uint_as_float(((u32)v) << 16); }
DEV u16 f2b(float f){ u32 u = __float_as_uint(f); return (u16)((u + 0x7fffu + ((u >> 16) & 1u)) >> 16); }
DEV float clip30(float x){ return fminf(fmaxf(x, -30.f), 30.f); }
DEV void up8(uint4 v, float* f){
  f[0]=b2f((u16)(v.x&0xffffu)); f[1]=b2f((u16)(v.x>>16));
  f[2]=b2f((u16)(v.y&0xffffu)); f[3]=b2f((u16)(v.y>>16));
  f[4]=b2f((u16)(v.z&0xffffu)); f[5]=b2f((u16)(v.z>>16));
  f[6]=b2f((u16)(v.w&0xffffu)); f[7]=b2f((u16)(v.w>>16));
}
DEV uint4 pk8(const float* f){
  uint4 v;
  v.x = (u32)f2b(f[0]) | ((u32)f2b(f[1])<<16);
  v.y = (u32)f2b(f[2]) | ((u32)f2b(f[3])<<16);
  v.z = (u32)f2b(f[4]) | ((u32)f2b(f[5])<<16);
  v.w = (u32)f2b(f[6]) | ((u32)f2b(f[7])<<16);
  return v;
}
DEV void unp16(uint4 v, u16* o){
  o[0]=(u16)(v.x&0xffffu); o[1]=(u16)(v.x>>16);
  o[2]=(u16)(v.y&0xffffu); o[3]=(u16)(v.y>>16);
  o[4]=(u16)(v.z&0xffffu); o[5]=(u16)(v.z>>16);
  o[6]=(u16)(v.w&0xffffu); o[7]=(u16)(v.w>>16);
}
DEV void gload16(const u16* g, u16* l){
  __builtin_amdgcn_global_load_lds(
      (const __attribute__((address_space(1))) u32*)g,
      (__attribute__((address_space(3))) u32*)l, 16, 0, 0);
}
#define ZF4 ((f32x4){0.f,0.f,0.f,0.f})

// ---------------------------------------------------------------- batched transposes
__global__ void transpose5_k(const float* __restrict__ w0, const float* __restrict__ w1,
    const float* __restrict__ w2, const float* __restrict__ w3, const float* __restrict__ w4,
    u16* __restrict__ o0, u16* __restrict__ o1, u16* __restrict__ o2,
    u16* __restrict__ o3, u16* __restrict__ o4){
  __shared__ float tile[32][33];
  const float* ins[5] = {w0,w1,w2,w3,w4};
  u16* outs[5] = {o0,o1,o2,o3,o4};
  const float* in = ins[blockIdx.z];
  u16* out = outs[blockIdx.z];
  int c0 = blockIdx.x*32, r0 = blockIdx.y*32;
  int tx = threadIdx.x, ty = threadIdx.y; // (32,8)
  #pragma unroll
  for (int j=0;j<4;j++) tile[ty + j*8][tx] = in[(size_t)(r0 + ty + j*8)*2048 + c0 + tx];
  __syncthreads();
  #pragma unroll
  for (int j=0;j<4;j++) out[(size_t)(c0 + ty + j*8)*2048 + r0 + tx] = f2b(tile[tx][ty + j*8]);
}

__global__ void transpose6_k(
    const float* __restrict__ i0, const float* __restrict__ i1, const float* __restrict__ i2,
    const float* __restrict__ i3, const float* __restrict__ i4, const float* __restrict__ i5,
    u16* __restrict__ o0, u16* __restrict__ o1, u16* __restrict__ o2,
    u16* __restrict__ o3, u16* __restrict__ o4, u16* __restrict__ o5){
  __shared__ float tile[32][33];
  const float* ins[6] = {i0,i1,i2,i3,i4,i5};
  u16* outs[6] = {o0,o1,o2,o3,o4,o5};
  const int Rs[6] = {2048, 192, 2048, 64, 2048, 96};
  const int Cs[6] = {192, 2048, 64, 2048, 96, 2048};
  int z = blockIdx.z;
  int R = Rs[z], C = Cs[z];
  int c0 = blockIdx.x*32, r0 = blockIdx.y*32;
  if (c0 >= C || r0 >= R) return;
  const float* in = ins[z];
  u16* out = outs[z];
  int tx = threadIdx.x, ty = threadIdx.y;
  #pragma unroll
  for (int j=0;j<4;j++) tile[ty + j*8][tx] = in[(size_t)(r0 + ty + j*8)*C + c0 + tx];
  __syncthreads();
  #pragma unroll
  for (int j=0;j<4;j++) out[(size_t)(c0 + ty + j*8)*R + r0 + tx] = f2b(tile[tx][ty + j*8]);
}

// ---------------------------------------------------------------- prep
__global__ __launch_bounds__(256) void prep_k(const float* __restrict__ x, const float* __restrict__ shift,
    const float* __restrict__ maax, u16* __restrict__ xmx, u16* __restrict__ dxp, float* __restrict__ out_xlast){
  int e8 = (blockIdx.x*256 + threadIdx.x) * 8;
  int row = e8 >> 11, col = e8 & 2047;
  int t = row & 4095, b = row >> 12;
  const float* xp = x + (size_t)row*2048 + col;
  const float* pp = t ? (x + (size_t)(row-1)*2048 + col) : (shift + (size_t)b*2048 + col);
  float xf[8], pf[8], mf[8], of[8], df[8];
  *(float4*)(xf)   = *(const float4*)(xp);
  *(float4*)(xf+4) = *(const float4*)(xp+4);
  *(float4*)(pf)   = *(const float4*)(pp);
  *(float4*)(pf+4) = *(const float4*)(pp+4);
  *(float4*)(mf)   = *(const float4*)(maax + col);
  *(float4*)(mf+4) = *(const float4*)(maax + col + 4);
  #pragma unroll
  for (int j=0;j<8;j++){ df[j] = pf[j]-xf[j]; of[j] = xf[j] + df[j]*mf[j]; }
  *(uint4*)(xmx + (size_t)row*2048 + col) = pk8(of);
  *(uint4*)(dxp + (size_t)row*2048 + col) = pk8(df);
  if (t == 4095){
    *(float4*)(out_xlast + (size_t)b*2048 + col)     = *(const float4*)(xf);
    *(float4*)(out_xlast + (size_t)b*2048 + col + 4) = *(const float4*)(xf+4);
  }
}

// ---------------------------------------------------------------- epilogue ids
enum { EPI_STORE=0, EPI_TANH=1, EPI_SILU=2, EPI_LERP=3, EPI_ICLR=5, EPI_STORE32=6 };

// ---------------------------------------------------------------- fused 6-way token-shift lerp
__global__ __launch_bounds__(256) void lerp6_k(
    const u16* __restrict__ xxx, const u16* __restrict__ w2t,
    const float* __restrict__ x, const u16* __restrict__ dxp,
    const float* __restrict__ ma0, const float* __restrict__ ma1, const float* __restrict__ ma2,
    const float* __restrict__ ma3, const float* __restrict__ ma4, const float* __restrict__ ma5,
    u16* __restrict__ o0, u16* __restrict__ o1, u16* __restrict__ o2,
    u16* __restrict__ o3, u16* __restrict__ o4, u16* __restrict__ o5)
{
  __shared__ u16 As[128][40];
  __shared__ u16 Bs[128][40];
  const int tid = threadIdx.x, lane = tid & 63, wid = tid >> 6;
  const int m0 = blockIdx.x*128, n0 = blockIdx.y*128;
  const int wrow = (wid>>1)*64, wcol = (wid&1)*64;
  const int fr = lane&15, kg = lane>>4;
  const int r_c0 = tid>>2, r_seg = tid&3, r_c1 = r_c0+64;
  const float* maap[6] = {ma0,ma1,ma2,ma3,ma4,ma5};
  u16* outs[6] = {o0,o1,o2,o3,o4,o5};

  float xv_[4][4][4], dxv_[4][4][4];
  #pragma unroll
  for (int m=0;m<4;m++)
    #pragma unroll
    for (int n=0;n<4;n++)
      #pragma unroll
      for (int q=0;q<4;q++){
        int row = m0 + wrow + m*16 + kg*4 + q;
        int col = n0 + wcol + n*16 + fr;
        xv_[m][n][q]  = x[(size_t)row*2048 + col];
        dxv_[m][n][q] = b2f(dxp[(size_t)row*2048 + col]);
      }

  #pragma unroll
  for (int s=0;s<6;s++){
    __syncthreads();
    *(uint4*)(&As[r_c0][r_seg*8]) = *(const uint4*)(xxx + (size_t)(m0+r_c0)*192 + s*32 + r_seg*8);
    *(uint4*)(&As[r_c1][r_seg*8]) = *(const uint4*)(xxx + (size_t)(m0+r_c1)*192 + s*32 + r_seg*8);
    *(uint4*)(&Bs[r_c0][r_seg*8]) = *(const uint4*)(w2t + (size_t)(n0+r_c0)*192 + s*32 + r_seg*8);
    *(uint4*)(&Bs[r_c1][r_seg*8]) = *(const uint4*)(w2t + (size_t)(n0+r_c1)*192 + s*32 + r_seg*8);
    __syncthreads();
    s16x8 a[4], bb[4];
    #pragma unroll
    for (int m=0;m<4;m++) a[m] = *(const s16x8*)(&As[wrow + m*16 + fr][kg*8]);
    #pragma unroll
    for (int n=0;n<4;n++) bb[n] = *(const s16x8*)(&Bs[wcol + n*16 + fr][kg*8]);
    f32x4 acc[4][4];
    #pragma unroll
    for (int m=0;m<4;m++)
      #pragma unroll
      for (int n=0;n<4;n++) acc[m][n] = ZF4;
    #pragma unroll
    for (int m=0;m<4;m++)
      #pragma unroll
      for (int n=0;n<4;n++)
        acc[m][n] = __builtin_amdgcn_mfma_f32_16x16x32_bf16(a[m], bb[n], acc[m][n], 0,0,0);
    #pragma unroll
    for (int n=0;n<4;n++){
      int col = n0 + wcol + n*16 + fr;
      float mv = maap[s][col];
      #pragma unroll
      for (int m=0;m<4;m++)
        #pragma unroll
        for (int q=0;q<4;q++){
          int row = m0 + wrow + m*16 + kg*4 + q;
          outs[s][(size_t)row*2048 + col] = f2b(xv_[m][n][q] + dxv_[m][n][q]*(mv + acc[m][n][q]));
        }
    }
  }
}

// ---------------------------------------------------------------- 256x256 BK=32, 16-wave counted-vmcnt GEMM
// XCD map: one n-panel per XCD -> per-XCD B slice = 1MB (L2-resident); A streams, L3-cached.
template<int EPI>
__global__ __launch_bounds__(1024) void gemm256_k(
    const u16* __restrict__ A, const u16* __restrict__ Bt,
    u16* __restrict__ Cout, float* __restrict__ Cout32,
    int M, int N, int K, const float* __restrict__ e_vec)
{
  __shared__ __align__(16) u16 lds[4*16384];   // 4 bufs x (A[256][32] + B[256][32]) = 128 KiB
  const int tid = threadIdx.x, lane = tid & 63;
  int bxx = blockIdx.x, byy = blockIdx.y;
  if (gridDim.x == 32 && gridDim.y == 8){
    int bid = byy * 32 + bxx;
    int xcd = bid & 7, idx = bid >> 3;     // idx 0..31
    byy = xcd;                             // n-panel pinned to XCD (B slice L2-resident)
    bxx = idx;                             // all 32 m-tiles inside the XCD
  } else {
    int nwg = gridDim.x * gridDim.y;
    if ((nwg & 7) == 0){
      int bid = byy * gridDim.x + bxx;
      int cpx = nwg >> 3;
      int swz = (bid & 7) * cpx + (bid >> 3);
      bxx = swz % gridDim.x; byy = swz / gridDim.x;
    }
  }
  const int m0 = bxx * 256, n0 = byy * 256;
  const int wid = tid >> 6;                    // 0..15
  const int wm = wid >> 2, wn = wid & 3;       // 4x4 wave grid; wave tile 64x64
  const int fr = lane & 15, kg = lane >> 4;
  const int NT = K >> 5;
  const int wchunk = __builtin_amdgcn_readfirstlane(wid);
  const int lr = lane >> 2, lsl = lane & 3;
  const int gswz = (lsl ^ ((lr >> 1) & 3)) << 3;
  const int kswz = (kg ^ ((fr >> 1) & 3)) << 3;

  f32x4 acc[4][4];
  #pragma unroll
  for (int m=0;m<4;m++)
    #pragma unroll
    for (int n=0;n<4;n++) acc[m][n] = ZF4;

  auto STAGE = [&](int t){
    u16* ab = lds + (t & 3) * 16384;
    u16* bb = ab + 8192;
    int gc = (t << 5) + gswz;
    int r = wchunk*16 + lr;
    gload16(A  + (size_t)(m0 + r)*K + gc, ab + wchunk*512);
    gload16(Bt + (size_t)(n0 + r)*K + gc, bb + wchunk*512);
  };

  STAGE(0);
  if (NT > 1) STAGE(1);
  if (NT > 2) STAGE(2);
  for (int t=0; t<NT; ++t){
    if (t+2 < NT)      { asm volatile("s_waitcnt vmcnt(4)" ::: "memory"); }
    else if (t+1 < NT) { asm volatile("s_waitcnt vmcnt(2)" ::: "memory"); }
    else               { asm volatile("s_waitcnt vmcnt(0)" ::: "memory"); }
    __builtin_amdgcn_s_barrier();
    __builtin_amdgcn_sched_barrier(0);
    if (t+3 < NT) STAGE(t+3);
    const u16* ab = lds + (t & 3) * 16384;
    const u16* bb = ab + 8192;
    s16x8 af[4], bf[4];
    #pragma unroll
    for (int m=0;m<4;m++){
      int r = wm*64 + m*16 + fr;
      af[m] = *(const s16x8*)(ab + r*32 + kswz);
    }
    #pragma unroll
    for (int n=0;n<4;n++){
      int r = wn*64 + n*16 + fr;
      bf[n] = *(const s16x8*)(bb + r*32 + kswz);
    }
    __builtin_amdgcn_s_setprio(1);
    #pragma unroll
    for (int m=0;m<4;m++)
      #pragma unroll
      for (int n=0;n<4;n++)
        acc[m][n] = __builtin_amdgcn_mfma_f32_16x16x32_bf16(af[m], bf[n], acc[m][n], 0,0,0);
    __builtin_amdgcn_s_setprio(0);
  }

  #pragma unroll
  for (int n=0;n<4;n++){
    int ccol = n0 + wn*64 + n*16 + fr;
    #pragma unroll
    for (int m=0;m<4;m++){
      #pragma unroll
      for (int q=0;q<4;q++){
        int row = m0 + wm*64 + m*16 + kg*4 + q;
        float v = acc[m][n][q];
        size_t oidx = (size_t)row*N + ccol;
        if constexpr (EPI == EPI_STORE) Cout[oidx] = f2b(v);
        else if constexpr (EPI == EPI_STORE32) Cout32[oidx] = v;
        else if constexpr (EPI == EPI_SILU) Cout[oidx] = f2b(v / (1.f + __expf(-v)));
        else if constexpr (EPI == EPI_ICLR) Cout[oidx] = f2b(1.f / (1.f + __expf(-(e_vec[ccol] + v))));
      }
    }
  }
}

// ---------------------------------------------------------------- paired thin GEMMs: z=0 (tanh) and z=1 (store)
__global__ __launch_bounds__(256) void thin2_k(
    const u16* __restrict__ A0, const u16* __restrict__ Bt0, u16* __restrict__ C0, int N0,
    const u16* __restrict__ A1, const u16* __restrict__ Bt1, u16* __restrict__ C1, int N1,
    int K)
{
  const u16* A  = blockIdx.z ? A1 : A0;
  const u16* Bt = blockIdx.z ? Bt1 : Bt0;
  u16* Cout     = blockIdx.z ? C1 : C0;
  const int N   = blockIdx.z ? N1 : N0;
  const int ldc = N;
  const bool do_tanh = (blockIdx.z == 0);
  const int m0 = blockIdx.x * 64, n0 = blockIdx.y * 64;
  if (n0 >= N) return;

  __shared__ u16 As[64][72];
  __shared__ u16 Bs[64][72];
  const int tid = threadIdx.x;
  const int lane = tid & 63, wid = tid >> 6;
  const int wrow = (wid >> 1) * 32, wcol = (wid & 1) * 32;
  const int fr = lane & 15, kg = lane >> 4;
  const int r_c = tid >> 2, r_seg = tid & 3;

  f32x4 acc[2][2];
  #pragma unroll
  for (int m=0;m<2;m++)
    #pragma unroll
    for (int n=0;n<2;n++) acc[m][n] = ZF4;

  for (int k0 = 0; k0 < K; k0 += 64) {
    __syncthreads();
    {
      const u16* as = A + (size_t)(m0 + r_c)*K + k0 + r_seg*16;
      *(uint4*)(&As[r_c][r_seg*16])     = *(const uint4*)(as);
      *(uint4*)(&As[r_c][r_seg*16 + 8]) = *(const uint4*)(as + 8);
      uint4 z = make_uint4(0,0,0,0);
      bool ok = (n0 + r_c < N);
      const u16* bs = Bt + (size_t)(n0 + r_c)*K + k0 + r_seg*16;
      *(uint4*)(&Bs[r_c][r_seg*16])     = ok ? *(const uint4*)(bs) : z;
      *(uint4*)(&Bs[r_c][r_seg*16 + 8]) = ok ? *(const uint4*)(bs + 8) : z;
    }
    __syncthreads();
    #pragma unroll
    for (int ks=0; ks<2; ++ks){
      s16x8 a[2], bb[2];
      #pragma unroll
      for (int m=0;m<2;m++) a[m] = *(const s16x8*)(&As[wrow + m*16 + fr][ks*32 + kg*8]);
      #pragma unroll
      for (int n=0;n<2;n++) bb[n] = *(const s16x8*)(&Bs[wcol + n*16 + fr][ks*32 + kg*8]);
      #pragma unroll
      for (int m=0;m<2;m++)
        #pragma unroll
        for (int n=0;n<2;n++)
          acc[m][n] = __builtin_amdgcn_mfma_f32_16x16x32_bf16(a[m], bb[n], acc[m][n], 0,0,0);
    }
  }
  #pragma unroll
  for (int n=0;n<2;n++){
    int ccol = n0 + wcol + n*16 + fr;
    if (ccol >= N) continue;
    #pragma unroll
    for (int m=0;m<2;m++){
      #pragma unroll
      for (int q=0;q<4;q++){
        int row = m0 + wrow + m*16 + kg*4 + q;
        float v = acc[m][n][q];
        Cout[(size_t)row*ldc + ccol] = f2b(do_tanh ? tanhf(v) : v);
      }
    }
  }
}

// ---------------------------------------------------------------- thin GEMM: 64x64 tile, BK=64
template<int EPI>
__global__ __launch_bounds__(256) void gemm_thin_k(
    const u16* __restrict__ A, int lda,
    const u16* __restrict__ Bt, int ldb,
    u16* __restrict__ Cout, int ldc, int N, int K)
{
  __shared__ u16 As[64][72];
  __shared__ u16 Bs[64][72];
  const int tid = threadIdx.x;
  const int lane = tid & 63, wid = tid >> 6;
  const int m0 = blockIdx.x * 64, n0 = blockIdx.y * 64;
  const int wrow = (wid >> 1) * 32, wcol = (wid & 1) * 32;
  const int fr = lane & 15, kg = lane >> 4;
  const int r_c = tid >> 2, r_seg = tid & 3;

  f32x4 acc[2][2];
  #pragma unroll
  for (int m=0;m<2;m++)
    #pragma unroll
    for (int n=0;n<2;n++) acc[m][n] = ZF4;

  for (int k0 = 0; k0 < K; k0 += 64) {
    __syncthreads();
    {
      const u16* as = A + (size_t)(m0 + r_c)*lda + k0 + r_seg*16;
      *(uint4*)(&As[r_c][r_seg*16])     = *(const uint4*)(as);
      *(uint4*)(&As[r_c][r_seg*16 + 8]) = *(const uint4*)(as + 8);
      uint4 z = make_uint4(0,0,0,0);
      bool ok = (n0 + r_c < N);
      const u16* bs = Bt + (size_t)(n0 + r_c)*ldb + k0 + r_seg*16;
      *(uint4*)(&Bs[r_c][r_seg*16])     = ok ? *(const uint4*)(bs) : z;
      *(uint4*)(&Bs[r_c][r_seg*16 + 8]) = ok ? *(const uint4*)(bs + 8) : z;
    }
    __syncthreads();
    #pragma unroll
    for (int ks=0; ks<2; ++ks){
      s16x8 a[2], bb[2];
      #pragma unroll
      for (int m=0;m<2;m++) a[m] = *(const s16x8*)(&As[wrow + m*16 + fr][ks*32 + kg*8]);
      #pragma unroll
      for (int n=0;n<2;n++) bb[n] = *(const s16x8*)(&Bs[wcol + n*16 + fr][ks*32 + kg*8]);
      #pragma unroll
      for (int m=0;m<2;m++)
        #pragma unroll
        for (int n=0;n<2;n++)
          acc[m][n] = __builtin_amdgcn_mfma_f32_16x16x32_bf16(a[m], bb[n], acc[m][n], 0,0,0);
    }
  }
  #pragma unroll
  for (int n=0;n<2;n++){
    int ccol = n0 + wcol + n*16 + fr;
    if (ccol >= N) continue;
    #pragma unroll
    for (int m=0;m<2;m++){
      #pragma unroll
      for (int q=0;q<4;q++){
        int row = m0 + wrow + m*16 + kg*4 + q;
        float v = acc[m][n][q];
        size_t oidx = (size_t)row*ldc + ccol;
        if constexpr (EPI == EPI_TANH) Cout[oidx] = f2b(tanhf(v));
        else Cout[oidx] = f2b(v);
      }
    }
  }
}

// ---------------------------------------------------------------- WKV phase 1: 1024 threads / 16 waves
// VALU/staging phases use 8-threads-per-row x 8 elems; MFMA phases keep the proven
// 8-wave mapping behind if(wid<8). All barriers hit by all 1024 threads.
__global__ __launch_bounds__(1024, 1) void wkv1_k(
    const u16* __restrict__ r_g, const u16* __restrict__ kraw_g, const u16* __restrict__ v_g,
    const u16* __restrict__ ic_g,
    const u16* __restrict__ t2_g, const u16* __restrict__ dw2t_g, const float* __restrict__ td_g,
    const float* __restrict__ u_g, const float* __restrict__ kkk_g, const float* __restrict__ kka_g,
    u16* __restrict__ y1_g, u16* __restrict__ rw_g,
    u16* __restrict__ kvab_g, float* __restrict__ wsA_g)
{
  __shared__ __align__(16) char arena[162304];
  float* WL   = (float*)(arena);
  float* WC   = (float*)(arena + 34816);
  u16* Abuf   = (u16*)(arena);
  u16* kkcT   = (u16*)(arena + 34816);
  float* diag_l = (float*)(arena + 68096);  // 128
  float* offs_l = diag_l + 128;             // 64
  float* wsum_l = offs_l + 64;              // 64
  float* u_l    = wsum_l + 64;              // 64
  float* kkk_l  = u_l + 64;                 // 64
  float* kka_l  = kkk_l + 64;               // 64
  float* td_l   = kka_l + 64;               // 64 -> ends 70144
  u16* rd_l   = (u16*)(arena + 70144);
  u16* vT_l   = (u16*)(arena + 70144);
  u16* ki_l   = (u16*)(arena + 88576);
  u16* kkwT_l = (u16*)(arena + 88576);
  u16* kwT_l  = (u16*)(arena + 107008);
  u16* ka_l   = (u16*)(arena + 125440);
  u16* kkb_l  = (u16*)(arena + 143872);
  u16* kaT_l  = (u16*)(arena + 143872);

  const int tid = threadIdx.x, lane = tid & 63, wid = tid >> 6;   // wid 0..15
  const int cb = blockIdx.x;
  const int c = cb >> 6, b = (cb >> 5) & 1, h = cb & 31;
  const size_t base = ((size_t)(b*4096 + c*128)) * 2048 + h*64;
  const int fr = lane & 15, kg = lane >> 4;
  const int tq = tid >> 3, kh = (tid & 7) * 8;    // 8 threads/row, 8 cols each

  // P0a: stage t2 [128][64] (1 uint4/thread) + dw2 [64][64] (tid<512)
  {
    const u16* t2s = t2_g + (size_t)(b*4096 + c*128 + tq)*64 + kh;
    *(uint4*)(&rd_l[tq*72 + kh]) = *(const uint4*)(t2s);
    if (tid < 512){
      int n = tid >> 3, sg2 = (tid & 7) * 8;
      *(uint4*)(&ki_l[n*72 + sg2]) = *(const uint4*)(dw2t_g + (size_t)(h*64 + n)*64 + sg2);
    }
  }
  if (tid < 64){
    u_l[tid]   = u_g[h*64 + tid];
    kkk_l[tid] = kkk_g[h*64 + tid];
    kka_l[tid] = kka_g[h*64 + tid];
    td_l[tid]  = td_g[h*64 + tid];
  }
  __syncthreads();
  // P0b (waves 0-7)
  if (wid < 8){
    f32x4 accW[4];
    #pragma unroll
    for (int n=0;n<4;n++) accW[n] = ZF4;
    #pragma unroll
    for (int ks=0; ks<2; ++ks){
      s16x8 af = *(const s16x8*)(&rd_l[(wid*16 + fr)*72 + ks*32 + kg*8]);
      #pragma unroll
      for (int n=0;n<4;n++){
        s16x8 bf = *(const s16x8*)(&ki_l[(n*16 + fr)*72 + ks*32 + kg*8]);
        accW[n] = __builtin_amdgcn_mfma_f32_16x16x32_bf16(af, bf, accW[n], 0,0,0);
      }
    }
    #pragma unroll
    for (int n=0;n<4;n++)
      #pragma unroll
      for (int q=0;q<4;q++){
        int t = wid*16 + kg*4 + q;
        int s = n*16 + fr;
        WL[t*65 + s] = -__expf(td_l[s] + accW[n][q]);
      }
  }
  __syncthreads();
  // scan: 16 waves x 4 cols
  for (int j=0;j<4;j++){
    int k = wid*4 + j;
    float v = WL[lane*65 + k];
    #pragma unroll
    for (int d=1; d<64; d<<=1){ float o = __shfl_up(v, d); if (lane >= d) v += o; }
    WC[lane*65 + k] = v;
    float carry = __shfl(v, 63);
    float v2 = WL[(64+lane)*65 + k];
    #pragma unroll
    for (int d=1; d<64; d<<=1){ float o = __shfl_up(v2, d); if (lane >= d) v2 += o; }
    v2 += carry;
    WC[(64+lane)*65 + k] = v2;
    float tot = __shfl(v2, 63);
    if (lane == 0){ offs_l[k] = carry; wsum_l[k] = tot; wsA_g[(size_t)cb*64 + k] = __expf(tot); }
  }
  __syncthreads();
  // P1+P2 merged (8 elems/thread): r/k/ic read ONCE
  {
    float rf[8], kf[8], icf[8], kkraw[8];
    const u16* rs  = r_g    + base + (size_t)tq*2048 + kh;
    const u16* ks_ = kraw_g + base + (size_t)tq*2048 + kh;
    const u16* is_ = ic_g   + base + (size_t)tq*2048 + kh;
    up8(*(const uint4*)(rs),  rf);
    up8(*(const uint4*)(ks_), kf);
    up8(*(const uint4*)(is_), icf);
    float ss = 0.f;
    #pragma unroll
    for (int e=0;e<8;e++){ kkraw[e] = kf[e]*kkk_l[kh+e]; ss += kkraw[e]*kkraw[e]; }
    ss += __shfl_xor(ss, 1);
    ss += __shfl_xor(ss, 2);
    ss += __shfl_xor(ss, 4);
    float rn = 1.f / fmaxf(sqrtf(ss), 1e-12f);
    float dpart = 0.f;
    float rdf[8], kif[8], rwf[8], kkb8[8], ka8[8];
    #pragma unroll
    for (int e=0;e<8;e++){
      int k = kh + e;
      float kadj = kf[e] * (1.f + (icf[e] - 1.f) * kka_l[k]);
      float wl = WL[tq*65+k], wc = WC[tq*65+k];
      float wcs = wc - wl;
      float off = offs_l[k], wsm = wsum_l[k];
      rdf[e] = rf[e] * __expf(clip30(wcs - off));
      kif[e] = kadj  * __expf(clip30(off - wc));
      rwf[e] = rf[e] * __expf(clip30(wcs));
      kwT_l[k*136 + tq] = f2b(kadj * __expf(clip30(wsm - wc)));
      dpart += rf[e] * u_l[k] * kadj;
      float kkv = kkraw[e]*rn;
      kkb8[e] = kkv; ka8[e] = kkv*icf[e];
    }
    *(uint4*)(&rd_l[tq*72 + kh])  = pk8(rdf);
    *(uint4*)(&ki_l[tq*72 + kh])  = pk8(kif);
    *(uint4*)(&kkb_l[tq*72 + kh]) = pk8(kkb8);
    *(uint4*)(&ka_l [tq*72 + kh]) = pk8(ka8);
    *(uint4*)(rw_g + base + (size_t)tq*2048 + kh) = pk8(rwf);
    dpart += __shfl_xor(dpart, 1);
    dpart += __shfl_xor(dpart, 2);
    dpart += __shfl_xor(dpart, 4);
    if ((tid & 7) == 0) diag_l[tq] = dpart;
  }
  __syncthreads();
  // P3 (waves 0-7)
  f32x4 accA[8];
  if (wid < 8){
    #pragma unroll
    for (int n=0;n<8;n++) accA[n] = ZF4;
    #pragma unroll
    for (int ks=0; ks<2; ++ks){
      s16x8 af = *(const s16x8*)(&rd_l[(wid*16 + fr)*72 + ks*32 + kg*8]);
      #pragma unroll
      for (int n=0;n<8;n++){
        s16x8 bf = *(const s16x8*)(&ki_l[(n*16 + fr)*72 + ks*32 + kg*8]);
        accA[n] = __builtin_amdgcn_mfma_f32_16x16x32_bf16(af, bf, accA[n], 0,0,0);
      }
    }
    #pragma unroll
    for (int n=0;n<8;n++)
      #pragma unroll
      for (int q=0;q<4;q++){
        int t = wid*16 + kg*4 + q;
        int s = n*16 + fr;
        float v = accA[n][q];
        v = (t > s) ? v : ((t == s) ? diag_l[t] : 0.f);
        accA[n][q] = v;
        Abuf[t*136 + s] = f2b(v);
      }
  }
  __syncthreads();
  // P4a (8 elems/thread)
  {
    float kkf[8];
    up8(*(const uint4*)(&kkb_l[tq*72 + kh]), kkf);
    #pragma unroll
    for (int e=0;e<8;e++){
      int k = kh + e;
      kkwT_l[k*136 + tq] = f2b(-kkf[e] * __expf(clip30(wsum_l[k] - WC[tq*65+k])));
    }
  }
  __syncthreads();
  // P4b (waves 0-7)
  if (wid < 8){
    f32x4 accC[8];
    #pragma unroll
    for (int n=0;n<8;n++) accC[n] = ZF4;
    #pragma unroll
    for (int ks=0; ks<2; ++ks){
      s16x8 af = *(const s16x8*)(&ka_l[(wid*16 + fr)*72 + ks*32 + kg*8]);
      #pragma unroll
      for (int n=0;n<8;n++){
        s16x8 bf = *(const s16x8*)(&kkb_l[(n*16 + fr)*72 + ks*32 + kg*8]);
        accC[n] = __builtin_amdgcn_mfma_f32_16x16x32_bf16(af, bf, accC[n], 0,0,0);
      }
    }
    #pragma unroll
    for (int n=0;n<8;n++)
      #pragma unroll
      for (int q=0;q<4;q++){
        int t = wid*16 + kg*4 + q;
        int s = n*16 + fr;
        kkcT[s*136 + t] = f2b((t > s) ? accC[n][q] : 0.f);
      }
  }
  __syncthreads();
  // P5a (8 elems/thread): vT + kaT (over dead kkb)
  {
    u16 el[8];
    unp16(*(const uint4*)(v_g + base + (size_t)tq*2048 + kh), el);
    #pragma unroll
    for (int e=0;e<8;e++) vT_l[(kh + e)*136 + tq] = el[e];
    u16 el2[8];
    unp16(*(const uint4*)(&ka_l[tq*72 + kh]), el2);
    #pragma unroll
    for (int e=0;e<8;e++) kaT_l[(kh + e)*136 + tq] = el2[e];
  }
  // P5b (waves 0-7)
  if (wid < 8){
    f32x4 accP[8];
    #pragma unroll
    for (int n=0;n<8;n++) accP[n] = ZF4;
    #pragma unroll
    for (int ks=0; ks<4; ++ks){
      s16x8 af = *(const s16x8*)(&Abuf[(wid*16 + fr)*136 + ks*32 + kg*8]);
      #pragma unroll
      for (int n=0;n<8;n++){
        s16x8 bf = *(const s16x8*)(&kkcT[(n*16 + fr)*136 + ks*32 + kg*8]);
        accP[n] = __builtin_amdgcn_mfma_f32_16x16x32_bf16(af, bf, accP[n], 0,0,0);
      }
    }
    #pragma unroll
    for (int n=0;n<8;n++)
      #pragma unroll
      for (int q=0;q<4;q++){
        int t = wid*16 + kg*4 + q;
        int s = n*16 + fr;
        float v = accA[n][q] - ((t >= s) ? accP[n][q] : 0.f);
        Abuf[t*136 + s] = f2b(v);
      }
  }
  __syncthreads();
  // P6 (waves 0-7)
  if (wid < 8){
    f32x4 accY[4];
    #pragma unroll
    for (int n=0;n<4;n++) accY[n] = ZF4;
    #pragma unroll
    for (int ks=0; ks<4; ++ks){
      s16x8 af = *(const s16x8*)(&Abuf[(wid*16 + fr)*136 + ks*32 + kg*8]);
      #pragma unroll
      for (int n=0;n<4;n++){
        s16x8 bf = *(const s16x8*)(&vT_l[(n*16 + fr)*136 + ks*32 + kg*8]);
        accY[n] = __builtin_amdgcn_mfma_f32_16x16x32_bf16(af, bf, accY[n], 0,0,0);
      }
    }
    #pragma unroll
    for (int n=0;n<4;n++)
      #pragma unroll
      for (int q=0;q<4;q++){
        int t = wid*16 + kg*4 + q;
        int vd = n*16 + fr;
        y1_g[base + (size_t)t*2048 + vd] = f2b(accY[n][q]);
      }
    // P7 (waves 0-7)
    const int isAB = wid >> 2, mrow = (wid & 3) * 16;
    const u16* Amat = isAB ? kkwT_l : kwT_l;
    const u16* Bmat = isAB ? kaT_l  : vT_l;
    f32x4 acc2[4];
    #pragma unroll
    for (int n=0;n<4;n++) acc2[n] = ZF4;
    #pragma unroll
    for (int ks=0; ks<4; ++ks){
      s16x8 af = *(const s16x8*)(&Amat[(mrow + fr)*136 + ks*32 + kg*8]);
      #pragma unroll
      for (int n=0;n<4;n++){
        s16x8 bf = *(const s16x8*)(&Bmat[(n*16 + fr)*136 + ks*32 + kg*8]);
        acc2[n] = __builtin_amdgcn_mfma_f32_16x16x32_bf16(af, bf, acc2[n], 0,0,0);
      }
    }
    u16* kvp = kvab_g + (size_t)cb*8192 + isAB*4096;
    #pragma unroll
    for (int n=0;n<4;n++)
      #pragma unroll
      for (int q=0;q<4;q++){
        int kd = mrow + kg*4 + q, vd = n*16 + fr;
        if (isAB) kvp[vd*64 + kd] = f2b(acc2[n][q]);
        else      kvp[kd*64 + vd] = f2b(acc2[n][q]);
      }
  }
}

// ---------------------------------------------------------------- WKV phase 2: MFMA state scan, 4-way row split
__global__ __launch_bounds__(256) void wkv2_k(
   const float* __restrict__ state_in, const u16* __restrict__ kvab_g,
   const float* __restrict__ wsA_g, float* __restrict__ sin_g, float* __restrict__ out_state)
{
  __shared__ u16 Sb[16][72];
  __shared__ u16 abT[64][72];
  const int tid = threadIdx.x, lane = tid & 63, wid = tid >> 6;
  const int blk = blockIdx.x;
  const int bh = blk >> 2, rg = blk & 3;
  const int b = bh >> 5, h = bh & 31;
  const int fr = lane & 15, kg = lane >> 4;
  const int lrow = kg*4;
  const int grow = rg*16 + lrow;
  const int vcol = wid*16 + fr;
  const int vrow = tid >> 2, jc = (tid & 3) * 16;

  f32x4 S;
  #pragma unroll
  for (int q=0;q<4;q++)
    S[q] = state_in[(size_t)bh*4096 + (size_t)(grow+q)*64 + vcol];

  uint4 pf_ab0, pf_ab1; u16 pf_kv[4]; float pf_ws;
  {
    int cb = b*32 + h;
    const u16* kvp = kvab_g + (size_t)cb*8192;
    pf_ab0 = *(const uint4*)(kvp + 4096 + vrow*64 + jc);
    pf_ab1 = *(const uint4*)(kvp + 4096 + vrow*64 + jc + 8);
    #pragma unroll
    for (int q=0;q<4;q++) pf_kv[q] = kvp[(grow+q)*64 + vcol];
    pf_ws = wsA_g[(size_t)cb*64 + vcol];
  }

  for (int c=0;c<32;c++){
    int cb = (c*2+b)*32 + h;
    *(uint4*)(&abT[vrow][jc])   = pf_ab0;
    *(uint4*)(&abT[vrow][jc+8]) = pf_ab1;
    #pragma unroll
    for (int q=0;q<4;q++) Sb[lrow+q][vcol] = f2b(S[q]);
    float kvf[4];
    #pragma unroll
    for (int q=0;q<4;q++) kvf[q] = b2f(pf_kv[q]);
    float wsf = pf_ws;
    float* sip = sin_g + (size_t)cb*4096;
    #pragma unroll
    for (int q=0;q<4;q++) sip[(size_t)(grow+q)*64 + vcol] = S[q];
    __syncthreads();
    if (c < 31){
      int cb2 = ((c+1)*2+b)*32 + h;
      const u16* kvp2 = kvab_g + (size_t)cb2*8192;
      pf_ab0 = *(const uint4*)(kvp2 + 4096 + vrow*64 + jc);
      pf_ab1 = *(const uint4*)(kvp2 + 4096 + vrow*64 + jc + 8);
      #pragma unroll
      for (int q=0;q<4;q++) pf_kv[q] = kvp2[(grow+q)*64 + vcol];
      pf_ws = wsA_g[(size_t)cb2*64 + vcol];
    }
    f32x4 acc = ZF4;
    #pragma unroll
    for (int ks=0; ks<2; ++ks){
      s16x8 a  = *(const s16x8*)(&Sb[fr][ks*32 + kg*8]);
      s16x8 bb = *(const s16x8*)(&abT[wid*16 + fr][ks*32 + kg*8]);
      acc = __builtin_amdgcn_mfma_f32_16x16x32_bf16(a, bb, acc, 0,0,0);
    }
    #pragma unroll
    for (int q=0;q<4;q++)
      S[q] = S[q]*wsf + acc[q] + kvf[q];
    __syncthreads();
  }
  #pragma unroll
  for (int q=0;q<4;q++)
    out_state[(size_t)bh*4096 + (size_t)(grow+q)*64 + vcol] = S[q];
}

// ---------------------------------------------------------------- WKV phase 3: MFMA y = y1 + rw@S_in, GroupNorm, *g
__global__ __launch_bounds__(256) void wkv3_k(
   const u16* __restrict__ y1_g, const u16* __restrict__ rw_g,
   const float* __restrict__ sin_g,
   const u16* __restrict__ g_g, const float* __restrict__ gnw, const float* __restrict__ gnb,
   u16* __restrict__ yf_g)
{
  __shared__ u16 rw_l[128][72];
  __shared__ u16 StT[64][72];   // S_in transposed, bf16: StT[vd][k]
  const int tid = threadIdx.x, lane = tid & 63, wid = tid >> 6;
  const int cb = blockIdx.x; int c = cb>>6, b = (cb>>5)&1, h = cb&31;
  size_t base = ((size_t)(b*4096 + c*128))*2048 + h*64;
  const int fr = lane & 15, kg = lane >> 4;
  const float* sip = sin_g + (size_t)cb*4096;
  #pragma unroll
  for (int j=0;j<16;j++){
    int flat = tid*16 + j;                 // k = flat>>6, vd = flat&63
    StT[flat & 63][flat >> 6] = f2b(sip[flat]);
  }
  {
    int t = tid>>1, kh2 = (tid&1)*32;
    const u16* rs = rw_g + base + (size_t)t*2048 + kh2;
    #pragma unroll
    for (int j=0;j<4;j++) *(uint4*)(&rw_l[t][kh2+j*8]) = *(const uint4*)(rs + j*8);
  }
  __syncthreads();
  f32x4 acc[2][4];
  #pragma unroll
  for (int mt=0;mt<2;mt++)
    #pragma unroll
    for (int n=0;n<4;n++) acc[mt][n] = ZF4;
  #pragma unroll
  for (int ks=0; ks<2; ++ks){
    s16x8 a[2];
    #pragma unroll
    for (int mt=0;mt<2;mt++) a[mt] = *(const s16x8*)(&rw_l[wid*32 + mt*16 + fr][ks*32 + kg*8]);
    #pragma unroll
    for (int n=0;n<4;n++){
      s16x8 bb = *(const s16x8*)(&StT[n*16 + fr][ks*32 + kg*8]);
      #pragma unroll
      for (int mt=0;mt<2;mt++)
        acc[mt][n] = __builtin_amdgcn_mfma_f32_16x16x32_bf16(a[mt], bb, acc[mt][n], 0,0,0);
    }
  }
  #pragma unroll
  for (int mt=0;mt<2;mt++){
    float yv[4][4], sum[4], sq[4];
    #pragma unroll
    for (int q=0;q<4;q++){ sum[q]=0.f; sq[q]=0.f; }
    #pragma unroll
    for (int n=0;n<4;n++){
      int vd = n*16 + fr;
      #pragma unroll
      for (int q=0;q<4;q++){
        int t = wid*32 + mt*16 + kg*4 + q;
        float v = acc[mt][n][q] + b2f(y1_g[base + (size_t)t*2048 + vd]);
        yv[n][q] = v; sum[q] += v; sq[q] += v*v;
      }
    }
    #pragma unroll
    for (int q=0;q<4;q++){
      #pragma unroll
      for (int d=1; d<16; d<<=1){
        sum[q] += __shfl_xor(sum[q], d);
        sq[q]  += __shfl_xor(sq[q],  d);
      }
    }
    #pragma unroll
    for (int n=0;n<4;n++){
      int vd = n*16 + fr;
      int ch = h*64 + vd;
      float gw = gnw[ch], gb = gnb[ch];
      #pragma unroll
      for (int q=0;q<4;q++){
        int t = wid*32 + mt*16 + kg*4 + q;
        float mean = sum[q] * (1.f/64.f);
        float var  = sq[q] * (1.f/64.f) - mean*mean;
        float rstd = rsqrtf(fmaxf(var, 0.f) + 6.4e-4f);
        size_t bt = (size_t)(b*4096 + c*128 + t);
        float val = (yv[n][q] - mean)*rstd * gw + gb;
        val *= b2f(g_g[bt*2048 + ch]);
        yf_g[base + (size_t)t*2048 + vd] = f2b(val);
      }
    }
  }
}

// ---------------------------------------------------------------- host
#define O_WTR   0ull
#define O_WTK   8388608ull
#define O_WTV   16777216ull
#define O_WTG   25165824ull
#define O_WTO   33554432ull
#define O_W1T   41943040ull
#define O_W2T   42729472ull
#define O_DW1T  43515904ull
#define O_DW2T  43778048ull
#define O_A1T   44040192ull
#define O_A2T   44433408ull
#define O_XXX   44826624ull
#define O_T2    47972352ull
#define O_T3    49020928ull
#define O_WSA   50593792ull
#define O_XMX   51118080ull       /* xmx -> xw -> r -> S_in(f32) */
#define O_A     84672512ull       /* xk -> v */
#define O_I     118226944ull      /* dxprev -> xa -> iclr */
#define O_R     151781376ull      /* xv -> g */
#define O_K     185335808ull      /* xr -> k -> y1 -> yf */
#define O_V     218890240ull      /* xg -> kvab */
#define WS_NEEDED 252444672ull

extern "C" void kernel_launch(void* const* d_in, const int* in_sizes, int n_in,
                              void* d_out, int out_size, void* d_ws, size_t ws_size,
                              hipStream_t stream)
{
  (void)in_sizes; (void)n_in; (void)out_size;
  if (ws_size < WS_NEEDED) return;
  const float* x     = (const float*)d_in[0];
  const float* shift = (const float*)d_in[1];
  const float* st_in = (const float*)d_in[2];
  const float* maax  = (const float*)d_in[3];
  const float* maas[6] = {(const float*)d_in[4],(const float*)d_in[5],(const float*)d_in[6],
                          (const float*)d_in[7],(const float*)d_in[8],(const float*)d_in[9]};
  const float* w1    = (const float*)d_in[10];
  const float* w2    = (const float*)d_in[11];
  const float* td    = (const float*)d_in[12];
  const float* dw1   = (const float*)d_in[13];
  const float* dw2   = (const float*)d_in[14];
  const float* faaaa = (const float*)d_in[15];
  const float* a0v   = (const float*)d_in[16];
  const float* a1w   = (const float*)d_in[17];
  const float* a2w   = (const float*)d_in[18];
  const float* kkk   = (const float*)d_in[19];
  const float* kka   = (const float*)d_in[20];
  const float* Wr    = (const float*)d_in[21];
  const float* Wk    = (const float*)d_in[22];
  const float* Wv    = (const float*)d_in[23];
  const float* Wg    = (const float*)d_in[24];
  const float* Wo    = (const float*)d_in[25];
  const float* gnw   = (const float*)d_in[26];
  const float* gnb   = (const float*)d_in[27];
  float* out = (float*)d_out;
  char* ws = (char*)d_ws;
  #define WSP(o) ((u16*)(ws + (o)))

  u16 *wtR=WSP(O_WTR), *wtK=WSP(O_WTK), *wtV=WSP(O_WTV), *wtG=WSP(O_WTG), *wtO=WSP(O_WTO);
  u16 *w1t=WSP(O_W1T), *w2t=WSP(O_W2T), *dw1t=WSP(O_DW1T), *dw2t=WSP(O_DW2T), *a1t=WSP(O_A1T), *a2t=WSP(O_A2T);
  u16 *xxx=WSP(O_XXX), *t2b=WSP(O_T2), *t3b=WSP(O_T3);
  u16 *sXMX=WSP(O_XMX), *sA=WSP(O_A), *sI=WSP(O_I), *sR=WSP(O_R), *sK=WSP(O_K), *sV=WSP(O_V);
  u16 *rw = WSP(O_WTR);
  float* sinF = (float*)(ws + O_XMX);
  float* wsA = (float*)(ws + O_WSA);
  float* out_xlast = out + 16777216;
  float* out_state = out + 16781312;

  dim3 tb(32,8);
  transpose5_k<<<dim3(64,64,5), tb, 0, stream>>>(Wr, Wk, Wv, Wg, Wo, wtR, wtK, wtV, wtG, wtO);
  transpose6_k<<<dim3(64,64,6), tb, 0, stream>>>(w1, w2, dw1, dw2, a1w, a2w,
                                                 w1t, w2t, dw1t, dw2t, a1t, a2t);

  prep_k<<<8192, 256, 0, stream>>>(x, shift, maax, sXMX /*xmx*/, sI /*dxp*/, out_xlast);

  // xxx = tanh(xmx @ w1)
  gemm_thin_k<EPI_TANH><<<dim3(128,3), 256, 0, stream>>>(sXMX, 2048, w1t, 2048, xxx, 192, 192, 2048);
  // all 6 token-shift lerps fused
  lerp6_k<<<dim3(64,16), 256, 0, stream>>>(xxx, w2t, x, sI /*dxp*/,
      maas[0], maas[1], maas[2], maas[3], maas[4], maas[5],
      sXMX /*xw*/, sA /*xk*/, sR /*xv*/, sK /*xr*/, sV /*xg*/, sI /*xa*/);
  // t2 = tanh(xw @ dw1) and t3 = xa @ a1 (paired)
  thin2_k<<<dim3(128,2,2), 256, 0, stream>>>(sXMX, dw1t, t2b, 64, sI, a1t, t3b, 96, 2048);
  // iclr = sigmoid(a0 + t3@a2) -> I   (gemm256 path, K=96)
  gemm256_k<EPI_ICLR><<<dim3(32,8), 1024, 0, stream>>>(t3b, a2t, sI, nullptr, 8192, 2048, 96, a0v);
  // big projections: r->XMX, k->K, v->A, g->R
  gemm256_k<EPI_STORE><<<dim3(32,8), 1024, 0, stream>>>(sK, wtR, sXMX, nullptr, 8192, 2048, 2048, nullptr);
  gemm256_k<EPI_STORE><<<dim3(32,8), 1024, 0, stream>>>(sA, wtK, sK, nullptr, 8192, 2048, 2048, nullptr);
  gemm256_k<EPI_STORE><<<dim3(32,8), 1024, 0, stream>>>(sR, wtV, sA, nullptr, 8192, 2048, 2048, nullptr);
  gemm256_k<EPI_SILU><<<dim3(32,8), 1024, 0, stream>>>(sV, wtG, sR, nullptr, 8192, 2048, 2048, nullptr);
  // wkv
  wkv1_k<<<2048, 1024, 0, stream>>>(sXMX, sK, sA, sI, t2b, dw2t, td, faaaa, kkk, kka,
                                    sK, rw, sV, wsA);
  wkv2_k<<<256, 256, 0, stream>>>(st_in, sV, wsA, sinF, out_state);
  wkv3_k<<<2048, 256, 0, stream>>>(sK, rw, sinF, sR /*g*/, gnw, gnb, sK /*yf in place*/);
  // out = yf @ W_o  (f32 store)
  gemm256_k<EPI_STORE32><<<dim3(32,8), 1024, 0, stream>>>(sK, wtO, nullptr, out, 8192, 2048, 2048, nullptr);
}

// Round 18
// 811.872 us; speedup vs baseline: 1.0412x; 1.0412x over previous
//
#include <hip/hip_runtime.h>

// RWKV7-delta time-mix. f32 in/out, bf16 intermediates + MFMA bf16 16x16x32.
// B=2 T=4096 C=2048 H=32 K=64 CHUNK=128 NC=32.
// Best-known configuration (r16, 813us): gemm256 16-wave + 4m-chunk XCD map,
// wkv1 512-thread (occupancy-insensitive, barrier-chain bound), MFMA wkv3.

typedef unsigned short u16;
typedef unsigned int   u32;
typedef __attribute__((ext_vector_type(8))) short s16x8;
typedef __attribute__((ext_vector_type(4))) float f32x4;

#define DEV __device__ __forceinline__

DEV float b2f(u16 v){ return __uint_as_float(((u32)v) << 16); }
DEV u16 f2b(float f){ u32 u = __float_as_uint(f); return (u16)((u + 0x7fffu + ((u >> 16) & 1u)) >> 16); }
DEV float clip30(float x){ return fminf(fmaxf(x, -30.f), 30.f); }
DEV void up8(uint4 v, float* f){
  f[0]=b2f((u16)(v.x&0xffffu)); f[1]=b2f((u16)(v.x>>16));
  f[2]=b2f((u16)(v.y&0xffffu)); f[3]=b2f((u16)(v.y>>16));
  f[4]=b2f((u16)(v.z&0xffffu)); f[5]=b2f((u16)(v.z>>16));
  f[6]=b2f((u16)(v.w&0xffffu)); f[7]=b2f((u16)(v.w>>16));
}
DEV uint4 pk8(const float* f){
  uint4 v;
  v.x = (u32)f2b(f[0]) | ((u32)f2b(f[1])<<16);
  v.y = (u32)f2b(f[2]) | ((u32)f2b(f[3])<<16);
  v.z = (u32)f2b(f[4]) | ((u32)f2b(f[5])<<16);
  v.w = (u32)f2b(f[6]) | ((u32)f2b(f[7])<<16);
  return v;
}
DEV void unp16(uint4 v, u16* o){
  o[0]=(u16)(v.x&0xffffu); o[1]=(u16)(v.x>>16);
  o[2]=(u16)(v.y&0xffffu); o[3]=(u16)(v.y>>16);
  o[4]=(u16)(v.z&0xffffu); o[5]=(u16)(v.z>>16);
  o[6]=(u16)(v.w&0xffffu); o[7]=(u16)(v.w>>16);
}
DEV void gload16(const u16* g, u16* l){
  __builtin_amdgcn_global_load_lds(
      (const __attribute__((address_space(1))) u32*)g,
      (__attribute__((address_space(3))) u32*)l, 16, 0, 0);
}
#define ZF4 ((f32x4){0.f,0.f,0.f,0.f})

// ---------------------------------------------------------------- batched transposes
__global__ void transpose5_k(const float* __restrict__ w0, const float* __restrict__ w1,
    const float* __restrict__ w2, const float* __restrict__ w3, const float* __restrict__ w4,
    u16* __restrict__ o0, u16* __restrict__ o1, u16* __restrict__ o2,
    u16* __restrict__ o3, u16* __restrict__ o4){
  __shared__ float tile[32][33];
  const float* ins[5] = {w0,w1,w2,w3,w4};
  u16* outs[5] = {o0,o1,o2,o3,o4};
  const float* in = ins[blockIdx.z];
  u16* out = outs[blockIdx.z];
  int c0 = blockIdx.x*32, r0 = blockIdx.y*32;
  int tx = threadIdx.x, ty = threadIdx.y; // (32,8)
  #pragma unroll
  for (int j=0;j<4;j++) tile[ty + j*8][tx] = in[(size_t)(r0 + ty + j*8)*2048 + c0 + tx];
  __syncthreads();
  #pragma unroll
  for (int j=0;j<4;j++) out[(size_t)(c0 + ty + j*8)*2048 + r0 + tx] = f2b(tile[tx][ty + j*8]);
}

__global__ void transpose6_k(
    const float* __restrict__ i0, const float* __restrict__ i1, const float* __restrict__ i2,
    const float* __restrict__ i3, const float* __restrict__ i4, const float* __restrict__ i5,
    u16* __restrict__ o0, u16* __restrict__ o1, u16* __restrict__ o2,
    u16* __restrict__ o3, u16* __restrict__ o4, u16* __restrict__ o5){
  __shared__ float tile[32][33];
  const float* ins[6] = {i0,i1,i2,i3,i4,i5};
  u16* outs[6] = {o0,o1,o2,o3,o4,o5};
  const int Rs[6] = {2048, 192, 2048, 64, 2048, 96};
  const int Cs[6] = {192, 2048, 64, 2048, 96, 2048};
  int z = blockIdx.z;
  int R = Rs[z], C = Cs[z];
  int c0 = blockIdx.x*32, r0 = blockIdx.y*32;
  if (c0 >= C || r0 >= R) return;
  const float* in = ins[z];
  u16* out = outs[z];
  int tx = threadIdx.x, ty = threadIdx.y;
  #pragma unroll
  for (int j=0;j<4;j++) tile[ty + j*8][tx] = in[(size_t)(r0 + ty + j*8)*C + c0 + tx];
  __syncthreads();
  #pragma unroll
  for (int j=0;j<4;j++) out[(size_t)(c0 + ty + j*8)*R + r0 + tx] = f2b(tile[tx][ty + j*8]);
}

// ---------------------------------------------------------------- prep
__global__ __launch_bounds__(256) void prep_k(const float* __restrict__ x, const float* __restrict__ shift,
    const float* __restrict__ maax, u16* __restrict__ xmx, u16* __restrict__ dxp, float* __restrict__ out_xlast){
  int e8 = (blockIdx.x*256 + threadIdx.x) * 8;
  int row = e8 >> 11, col = e8 & 2047;
  int t = row & 4095, b = row >> 12;
  const float* xp = x + (size_t)row*2048 + col;
  const float* pp = t ? (x + (size_t)(row-1)*2048 + col) : (shift + (size_t)b*2048 + col);
  float xf[8], pf[8], mf[8], of[8], df[8];
  *(float4*)(xf)   = *(const float4*)(xp);
  *(float4*)(xf+4) = *(const float4*)(xp+4);
  *(float4*)(pf)   = *(const float4*)(pp);
  *(float4*)(pf+4) = *(const float4*)(pp+4);
  *(float4*)(mf)   = *(const float4*)(maax + col);
  *(float4*)(mf+4) = *(const float4*)(maax + col + 4);
  #pragma unroll
  for (int j=0;j<8;j++){ df[j] = pf[j]-xf[j]; of[j] = xf[j] + df[j]*mf[j]; }
  *(uint4*)(xmx + (size_t)row*2048 + col) = pk8(of);
  *(uint4*)(dxp + (size_t)row*2048 + col) = pk8(df);
  if (t == 4095){
    *(float4*)(out_xlast + (size_t)b*2048 + col)     = *(const float4*)(xf);
    *(float4*)(out_xlast + (size_t)b*2048 + col + 4) = *(const float4*)(xf+4);
  }
}

// ---------------------------------------------------------------- epilogue ids
enum { EPI_STORE=0, EPI_TANH=1, EPI_SILU=2, EPI_LERP=3, EPI_ICLR=5, EPI_STORE32=6 };

// ---------------------------------------------------------------- fused 6-way token-shift lerp
__global__ __launch_bounds__(256) void lerp6_k(
    const u16* __restrict__ xxx, const u16* __restrict__ w2t,
    const float* __restrict__ x, const u16* __restrict__ dxp,
    const float* __restrict__ ma0, const float* __restrict__ ma1, const float* __restrict__ ma2,
    const float* __restrict__ ma3, const float* __restrict__ ma4, const float* __restrict__ ma5,
    u16* __restrict__ o0, u16* __restrict__ o1, u16* __restrict__ o2,
    u16* __restrict__ o3, u16* __restrict__ o4, u16* __restrict__ o5)
{
  __shared__ u16 As[128][40];
  __shared__ u16 Bs[128][40];
  const int tid = threadIdx.x, lane = tid & 63, wid = tid >> 6;
  const int m0 = blockIdx.x*128, n0 = blockIdx.y*128;
  const int wrow = (wid>>1)*64, wcol = (wid&1)*64;
  const int fr = lane&15, kg = lane>>4;
  const int r_c0 = tid>>2, r_seg = tid&3, r_c1 = r_c0+64;
  const float* maap[6] = {ma0,ma1,ma2,ma3,ma4,ma5};
  u16* outs[6] = {o0,o1,o2,o3,o4,o5};

  float xv_[4][4][4], dxv_[4][4][4];
  #pragma unroll
  for (int m=0;m<4;m++)
    #pragma unroll
    for (int n=0;n<4;n++)
      #pragma unroll
      for (int q=0;q<4;q++){
        int row = m0 + wrow + m*16 + kg*4 + q;
        int col = n0 + wcol + n*16 + fr;
        xv_[m][n][q]  = x[(size_t)row*2048 + col];
        dxv_[m][n][q] = b2f(dxp[(size_t)row*2048 + col]);
      }

  #pragma unroll
  for (int s=0;s<6;s++){
    __syncthreads();
    *(uint4*)(&As[r_c0][r_seg*8]) = *(const uint4*)(xxx + (size_t)(m0+r_c0)*192 + s*32 + r_seg*8);
    *(uint4*)(&As[r_c1][r_seg*8]) = *(const uint4*)(xxx + (size_t)(m0+r_c1)*192 + s*32 + r_seg*8);
    *(uint4*)(&Bs[r_c0][r_seg*8]) = *(const uint4*)(w2t + (size_t)(n0+r_c0)*192 + s*32 + r_seg*8);
    *(uint4*)(&Bs[r_c1][r_seg*8]) = *(const uint4*)(w2t + (size_t)(n0+r_c1)*192 + s*32 + r_seg*8);
    __syncthreads();
    s16x8 a[4], bb[4];
    #pragma unroll
    for (int m=0;m<4;m++) a[m] = *(const s16x8*)(&As[wrow + m*16 + fr][kg*8]);
    #pragma unroll
    for (int n=0;n<4;n++) bb[n] = *(const s16x8*)(&Bs[wcol + n*16 + fr][kg*8]);
    f32x4 acc[4][4];
    #pragma unroll
    for (int m=0;m<4;m++)
      #pragma unroll
      for (int n=0;n<4;n++) acc[m][n] = ZF4;
    #pragma unroll
    for (int m=0;m<4;m++)
      #pragma unroll
      for (int n=0;n<4;n++)
        acc[m][n] = __builtin_amdgcn_mfma_f32_16x16x32_bf16(a[m], bb[n], acc[m][n], 0,0,0);
    #pragma unroll
    for (int n=0;n<4;n++){
      int col = n0 + wcol + n*16 + fr;
      float mv = maap[s][col];
      #pragma unroll
      for (int m=0;m<4;m++)
        #pragma unroll
        for (int q=0;q<4;q++){
          int row = m0 + wrow + m*16 + kg*4 + q;
          outs[s][(size_t)row*2048 + col] = f2b(xv_[m][n][q] + dxv_[m][n][q]*(mv + acc[m][n][q]));
        }
    }
  }
}

// ---------------------------------------------------------------- 256x256 BK=32, 16-wave counted-vmcnt GEMM
template<int EPI>
__global__ __launch_bounds__(1024) void gemm256_k(
    const u16* __restrict__ A, const u16* __restrict__ Bt,
    u16* __restrict__ Cout, float* __restrict__ Cout32,
    int M, int N, int K, const float* __restrict__ e_vec)
{
  __shared__ __align__(16) u16 lds[4*16384];   // 4 bufs x (A[256][32] + B[256][32]) = 128 KiB
  const int tid = threadIdx.x, lane = tid & 63;
  int bxx = blockIdx.x, byy = blockIdx.y;
  if (gridDim.x == 32 && gridDim.y == 8){
    int bid = byy * 32 + bxx;
    int xcd = bid & 7, idx = bid >> 3;
    bxx = xcd*4 + (idx & 3);
    byy = idx >> 2;
  } else {
    int nwg = gridDim.x * gridDim.y;
    if ((nwg & 7) == 0){
      int bid = byy * gridDim.x + bxx;
      int cpx = nwg >> 3;
      int swz = (bid & 7) * cpx + (bid >> 3);
      bxx = swz % gridDim.x; byy = swz / gridDim.x;
    }
  }
  const int m0 = bxx * 256, n0 = byy * 256;
  const int wid = tid >> 6;                    // 0..15
  const int wm = wid >> 2, wn = wid & 3;       // 4x4 wave grid; wave tile 64x64
  const int fr = lane & 15, kg = lane >> 4;
  const int NT = K >> 5;
  const int wchunk = __builtin_amdgcn_readfirstlane(wid);
  const int lr = lane >> 2, lsl = lane & 3;
  const int gswz = (lsl ^ ((lr >> 1) & 3)) << 3;
  const int kswz = (kg ^ ((fr >> 1) & 3)) << 3;

  f32x4 acc[4][4];
  #pragma unroll
  for (int m=0;m<4;m++)
    #pragma unroll
    for (int n=0;n<4;n++) acc[m][n] = ZF4;

  auto STAGE = [&](int t){
    u16* ab = lds + (t & 3) * 16384;
    u16* bb = ab + 8192;
    int gc = (t << 5) + gswz;
    int r = wchunk*16 + lr;
    gload16(A  + (size_t)(m0 + r)*K + gc, ab + wchunk*512);
    gload16(Bt + (size_t)(n0 + r)*K + gc, bb + wchunk*512);
  };

  STAGE(0);
  if (NT > 1) STAGE(1);
  if (NT > 2) STAGE(2);
  for (int t=0; t<NT; ++t){
    if (t+2 < NT)      { asm volatile("s_waitcnt vmcnt(4)" ::: "memory"); }
    else if (t+1 < NT) { asm volatile("s_waitcnt vmcnt(2)" ::: "memory"); }
    else               { asm volatile("s_waitcnt vmcnt(0)" ::: "memory"); }
    __builtin_amdgcn_s_barrier();
    __builtin_amdgcn_sched_barrier(0);
    if (t+3 < NT) STAGE(t+3);
    const u16* ab = lds + (t & 3) * 16384;
    const u16* bb = ab + 8192;
    s16x8 af[4], bf[4];
    #pragma unroll
    for (int m=0;m<4;m++){
      int r = wm*64 + m*16 + fr;
      af[m] = *(const s16x8*)(ab + r*32 + kswz);
    }
    #pragma unroll
    for (int n=0;n<4;n++){
      int r = wn*64 + n*16 + fr;
      bf[n] = *(const s16x8*)(bb + r*32 + kswz);
    }
    __builtin_amdgcn_s_setprio(1);
    #pragma unroll
    for (int m=0;m<4;m++)
      #pragma unroll
      for (int n=0;n<4;n++)
        acc[m][n] = __builtin_amdgcn_mfma_f32_16x16x32_bf16(af[m], bf[n], acc[m][n], 0,0,0);
    __builtin_amdgcn_s_setprio(0);
  }

  #pragma unroll
  for (int n=0;n<4;n++){
    int ccol = n0 + wn*64 + n*16 + fr;
    #pragma unroll
    for (int m=0;m<4;m++){
      #pragma unroll
      for (int q=0;q<4;q++){
        int row = m0 + wm*64 + m*16 + kg*4 + q;
        float v = acc[m][n][q];
        size_t oidx = (size_t)row*N + ccol;
        if constexpr (EPI == EPI_STORE) Cout[oidx] = f2b(v);
        else if constexpr (EPI == EPI_STORE32) Cout32[oidx] = v;
        else if constexpr (EPI == EPI_SILU) Cout[oidx] = f2b(v / (1.f + __expf(-v)));
        else if constexpr (EPI == EPI_ICLR) Cout[oidx] = f2b(1.f / (1.f + __expf(-(e_vec[ccol] + v))));
      }
    }
  }
}

// ---------------------------------------------------------------- paired thin GEMMs: z=0 (tanh) and z=1 (store)
__global__ __launch_bounds__(256) void thin2_k(
    const u16* __restrict__ A0, const u16* __restrict__ Bt0, u16* __restrict__ C0, int N0,
    const u16* __restrict__ A1, const u16* __restrict__ Bt1, u16* __restrict__ C1, int N1,
    int K)
{
  const u16* A  = blockIdx.z ? A1 : A0;
  const u16* Bt = blockIdx.z ? Bt1 : Bt0;
  u16* Cout     = blockIdx.z ? C1 : C0;
  const int N   = blockIdx.z ? N1 : N0;
  const int ldc = N;
  const bool do_tanh = (blockIdx.z == 0);
  const int m0 = blockIdx.x * 64, n0 = blockIdx.y * 64;
  if (n0 >= N) return;

  __shared__ u16 As[64][72];
  __shared__ u16 Bs[64][72];
  const int tid = threadIdx.x;
  const int lane = tid & 63, wid = tid >> 6;
  const int wrow = (wid >> 1) * 32, wcol = (wid & 1) * 32;
  const int fr = lane & 15, kg = lane >> 4;
  const int r_c = tid >> 2, r_seg = tid & 3;

  f32x4 acc[2][2];
  #pragma unroll
  for (int m=0;m<2;m++)
    #pragma unroll
    for (int n=0;n<2;n++) acc[m][n] = ZF4;

  for (int k0 = 0; k0 < K; k0 += 64) {
    __syncthreads();
    {
      const u16* as = A + (size_t)(m0 + r_c)*K + k0 + r_seg*16;
      *(uint4*)(&As[r_c][r_seg*16])     = *(const uint4*)(as);
      *(uint4*)(&As[r_c][r_seg*16 + 8]) = *(const uint4*)(as + 8);
      uint4 z = make_uint4(0,0,0,0);
      bool ok = (n0 + r_c < N);
      const u16* bs = Bt + (size_t)(n0 + r_c)*K + k0 + r_seg*16;
      *(uint4*)(&Bs[r_c][r_seg*16])     = ok ? *(const uint4*)(bs) : z;
      *(uint4*)(&Bs[r_c][r_seg*16 + 8]) = ok ? *(const uint4*)(bs + 8) : z;
    }
    __syncthreads();
    #pragma unroll
    for (int ks=0; ks<2; ++ks){
      s16x8 a[2], bb[2];
      #pragma unroll
      for (int m=0;m<2;m++) a[m] = *(const s16x8*)(&As[wrow + m*16 + fr][ks*32 + kg*8]);
      #pragma unroll
      for (int n=0;n<2;n++) bb[n] = *(const s16x8*)(&Bs[wcol + n*16 + fr][ks*32 + kg*8]);
      #pragma unroll
      for (int m=0;m<2;m++)
        #pragma unroll
        for (int n=0;n<2;n++)
          acc[m][n] = __builtin_amdgcn_mfma_f32_16x16x32_bf16(a[m], bb[n], acc[m][n], 0,0,0);
    }
  }
  #pragma unroll
  for (int n=0;n<2;n++){
    int ccol = n0 + wcol + n*16 + fr;
    if (ccol >= N) continue;
    #pragma unroll
    for (int m=0;m<2;m++){
      #pragma unroll
      for (int q=0;q<4;q++){
        int row = m0 + wrow + m*16 + kg*4 + q;
        float v = acc[m][n][q];
        Cout[(size_t)row*ldc + ccol] = f2b(do_tanh ? tanhf(v) : v);
      }
    }
  }
}

// ---------------------------------------------------------------- thin GEMM: 64x64 tile, BK=64
template<int EPI>
__global__ __launch_bounds__(256) void gemm_thin_k(
    const u16* __restrict__ A, int lda,
    const u16* __restrict__ Bt, int ldb,
    u16* __restrict__ Cout, int ldc, int N, int K)
{
  __shared__ u16 As[64][72];
  __shared__ u16 Bs[64][72];
  const int tid = threadIdx.x;
  const int lane = tid & 63, wid = tid >> 6;
  const int m0 = blockIdx.x * 64, n0 = blockIdx.y * 64;
  const int wrow = (wid >> 1) * 32, wcol = (wid & 1) * 32;
  const int fr = lane & 15, kg = lane >> 4;
  const int r_c = tid >> 2, r_seg = tid & 3;

  f32x4 acc[2][2];
  #pragma unroll
  for (int m=0;m<2;m++)
    #pragma unroll
    for (int n=0;n<2;n++) acc[m][n] = ZF4;

  for (int k0 = 0; k0 < K; k0 += 64) {
    __syncthreads();
    {
      const u16* as = A + (size_t)(m0 + r_c)*lda + k0 + r_seg*16;
      *(uint4*)(&As[r_c][r_seg*16])     = *(const uint4*)(as);
      *(uint4*)(&As[r_c][r_seg*16 + 8]) = *(const uint4*)(as + 8);
      uint4 z = make_uint4(0,0,0,0);
      bool ok = (n0 + r_c < N);
      const u16* bs = Bt + (size_t)(n0 + r_c)*ldb + k0 + r_seg*16;
      *(uint4*)(&Bs[r_c][r_seg*16])     = ok ? *(const uint4*)(bs) : z;
      *(uint4*)(&Bs[r_c][r_seg*16 + 8]) = ok ? *(const uint4*)(bs + 8) : z;
    }
    __syncthreads();
    #pragma unroll
    for (int ks=0; ks<2; ++ks){
      s16x8 a[2], bb[2];
      #pragma unroll
      for (int m=0;m<2;m++) a[m] = *(const s16x8*)(&As[wrow + m*16 + fr][ks*32 + kg*8]);
      #pragma unroll
      for (int n=0;n<2;n++) bb[n] = *(const s16x8*)(&Bs[wcol + n*16 + fr][ks*32 + kg*8]);
      #pragma unroll
      for (int m=0;m<2;m++)
        #pragma unroll
        for (int n=0;n<2;n++)
          acc[m][n] = __builtin_amdgcn_mfma_f32_16x16x32_bf16(a[m], bb[n], acc[m][n], 0,0,0);
    }
  }
  #pragma unroll
  for (int n=0;n<2;n++){
    int ccol = n0 + wcol + n*16 + fr;
    if (ccol >= N) continue;
    #pragma unroll
    for (int m=0;m<2;m++){
      #pragma unroll
      for (int q=0;q<4;q++){
        int row = m0 + wrow + m*16 + kg*4 + q;
        float v = acc[m][n][q];
        size_t oidx = (size_t)row*ldc + ccol;
        if constexpr (EPI == EPI_TANH) Cout[oidx] = f2b(tanhf(v));
        else Cout[oidx] = f2b(v);
      }
    }
  }
}

// ---------------------------------------------------------------- WKV phase 1 (512 threads, P1+P2 merged)
__global__ __launch_bounds__(512, 1) void wkv1_k(
    const u16* __restrict__ r_g, const u16* __restrict__ kraw_g, const u16* __restrict__ v_g,
    const u16* __restrict__ ic_g,
    const u16* __restrict__ t2_g, const u16* __restrict__ dw2t_g, const float* __restrict__ td_g,
    const float* __restrict__ u_g, const float* __restrict__ kkk_g, const float* __restrict__ kka_g,
    u16* __restrict__ y1_g, u16* __restrict__ rw_g,
    u16* __restrict__ kvab_g, float* __restrict__ wsA_g)
{
  __shared__ __align__(16) char arena[162304];
  float* WL   = (float*)(arena);
  float* WC   = (float*)(arena + 34816);
  u16* Abuf   = (u16*)(arena);
  u16* kkcT   = (u16*)(arena + 34816);
  float* diag_l = (float*)(arena + 68096);  // 128
  float* offs_l = diag_l + 128;             // 64
  float* wsum_l = offs_l + 64;              // 64
  float* u_l    = wsum_l + 64;              // 64
  float* kkk_l  = u_l + 64;                 // 64
  float* kka_l  = kkk_l + 64;               // 64
  float* td_l   = kka_l + 64;               // 64 -> ends 70144
  u16* rd_l   = (u16*)(arena + 70144);
  u16* vT_l   = (u16*)(arena + 70144);
  u16* ki_l   = (u16*)(arena + 88576);
  u16* kkwT_l = (u16*)(arena + 88576);
  u16* kwT_l  = (u16*)(arena + 107008);
  u16* ka_l   = (u16*)(arena + 125440);
  u16* kkb_l  = (u16*)(arena + 143872);
  u16* kaT_l  = (u16*)(arena + 143872);

  const int tid = threadIdx.x, lane = tid & 63, wid = tid >> 6;
  const int cb = blockIdx.x;
  const int c = cb >> 6, b = (cb >> 5) & 1, h = cb & 31;
  const size_t base = ((size_t)(b*4096 + c*128)) * 2048 + h*64;
  const int fr = lane & 15, kg = lane >> 4;
  const int tq = tid >> 2, kh = (tid & 3) * 16;

  // P0a
  {
    const u16* t2s = t2_g + (size_t)(b*4096 + c*128 + tq)*64 + kh;
    *(uint4*)(&rd_l[tq*72 + kh])     = *(const uint4*)(t2s);
    *(uint4*)(&rd_l[tq*72 + kh + 8]) = *(const uint4*)(t2s + 8);
    int n = tid >> 3, sg2 = (tid & 7) * 8;
    *(uint4*)(&ki_l[n*72 + sg2]) = *(const uint4*)(dw2t_g + (size_t)(h*64 + n)*64 + sg2);
  }
  if (tid < 64){
    u_l[tid]   = u_g[h*64 + tid];
    kkk_l[tid] = kkk_g[h*64 + tid];
    kka_l[tid] = kka_g[h*64 + tid];
    td_l[tid]  = td_g[h*64 + tid];
  }
  __syncthreads();
  // P0b
  {
    f32x4 accW[4];
    #pragma unroll
    for (int n=0;n<4;n++) accW[n] = ZF4;
    #pragma unroll
    for (int ks=0; ks<2; ++ks){
      s16x8 af = *(const s16x8*)(&rd_l[(wid*16 + fr)*72 + ks*32 + kg*8]);
      #pragma unroll
      for (int n=0;n<4;n++){
        s16x8 bf = *(const s16x8*)(&ki_l[(n*16 + fr)*72 + ks*32 + kg*8]);
        accW[n] = __builtin_amdgcn_mfma_f32_16x16x32_bf16(af, bf, accW[n], 0,0,0);
      }
    }
    #pragma unroll
    for (int n=0;n<4;n++)
      #pragma unroll
      for (int q=0;q<4;q++){
        int t = wid*16 + kg*4 + q;
        int s = n*16 + fr;
        WL[t*65 + s] = -__expf(td_l[s] + accW[n][q]);
      }
  }
  __syncthreads();
  // scan
  for (int j=0;j<8;j++){
    int k = wid*8 + j;
    float v = WL[lane*65 + k];
    #pragma unroll
    for (int d=1; d<64; d<<=1){ float o = __shfl_up(v, d); if (lane >= d) v += o; }
    WC[lane*65 + k] = v;
    float carry = __shfl(v, 63);
    float v2 = WL[(64+lane)*65 + k];
    #pragma unroll
    for (int d=1; d<64; d<<=1){ float o = __shfl_up(v2, d); if (lane >= d) v2 += o; }
    v2 += carry;
    WC[(64+lane)*65 + k] = v2;
    float tot = __shfl(v2, 63);
    if (lane == 0){ offs_l[k] = carry; wsum_l[k] = tot; wsA_g[(size_t)cb*64 + k] = __expf(tot); }
  }
  __syncthreads();
  // P1+P2 merged: r/k/ic read ONCE
  {
    float rf[16], kf[16], icf[16], kkraw[16];
    const u16* rs  = r_g    + base + (size_t)tq*2048 + kh;
    const u16* ks_ = kraw_g + base + (size_t)tq*2048 + kh;
    const u16* is_ = ic_g   + base + (size_t)tq*2048 + kh;
    up8(*(const uint4*)(rs),     rf);     up8(*(const uint4*)(rs + 8), rf + 8);
    up8(*(const uint4*)(ks_),    kf);     up8(*(const uint4*)(ks_ + 8), kf + 8);
    up8(*(const uint4*)(is_),    icf);    up8(*(const uint4*)(is_ + 8), icf + 8);
    float ss = 0.f;
    #pragma unroll
    for (int e=0;e<16;e++){ kkraw[e] = kf[e]*kkk_l[kh+e]; ss += kkraw[e]*kkraw[e]; }
    ss += __shfl_xor(ss, 1);
    ss += __shfl_xor(ss, 2);
    float rn = 1.f / fmaxf(sqrtf(ss), 1e-12f);
    float dpart = 0.f;
    #pragma unroll
    for (int j=0;j<2;j++){
      float rdf[8], kif[8], rwf[8], kkb8[8], ka8[8];
      #pragma unroll
      for (int e=0;e<8;e++){
        int i = j*8 + e;
        int k = kh + i;
        float kadj = kf[i] * (1.f + (icf[i] - 1.f) * kka_l[k]);
        float wl = WL[tq*65+k], wc = WC[tq*65+k];
        float wcs = wc - wl;
        float off = offs_l[k], wsm = wsum_l[k];
        rdf[e] = rf[i] * __expf(clip30(wcs - off));
        kif[e] = kadj  * __expf(clip30(off - wc));
        rwf[e] = rf[i] * __expf(clip30(wcs));
        kwT_l[k*136 + tq] = f2b(kadj * __expf(clip30(wsm - wc)));
        dpart += rf[i] * u_l[k] * kadj;
        float kkv = kkraw[i]*rn;
        kkb8[e] = kkv; ka8[e] = kkv*icf[i];
      }
      *(uint4*)(&rd_l[tq*72 + kh + j*8])  = pk8(rdf);
      *(uint4*)(&ki_l[tq*72 + kh + j*8])  = pk8(kif);
      *(uint4*)(&kkb_l[tq*72 + kh + j*8]) = pk8(kkb8);
      *(uint4*)(&ka_l [tq*72 + kh + j*8]) = pk8(ka8);
      *(uint4*)(rw_g + base + (size_t)tq*2048 + kh + j*8) = pk8(rwf);
    }
    dpart += __shfl_xor(dpart, 1);
    dpart += __shfl_xor(dpart, 2);
    if ((tid & 3) == 0) diag_l[tq] = dpart;
  }
  __syncthreads();
  // P3
  f32x4 accA[8];
  #pragma unroll
  for (int n=0;n<8;n++) accA[n] = ZF4;
  #pragma unroll
  for (int ks=0; ks<2; ++ks){
    s16x8 af = *(const s16x8*)(&rd_l[(wid*16 + fr)*72 + ks*32 + kg*8]);
    #pragma unroll
    for (int n=0;n<8;n++){
      s16x8 bf = *(const s16x8*)(&ki_l[(n*16 + fr)*72 + ks*32 + kg*8]);
      accA[n] = __builtin_amdgcn_mfma_f32_16x16x32_bf16(af, bf, accA[n], 0,0,0);
    }
  }
  #pragma unroll
  for (int n=0;n<8;n++)
    #pragma unroll
    for (int q=0;q<4;q++){
      int t = wid*16 + kg*4 + q;
      int s = n*16 + fr;
      float v = accA[n][q];
      v = (t > s) ? v : ((t == s) ? diag_l[t] : 0.f);
      accA[n][q] = v;
      Abuf[t*136 + s] = f2b(v);
    }
  __syncthreads();
  // P4a
  {
    #pragma unroll
    for (int j=0;j<2;j++){
      float kkf[8];
      up8(*(const uint4*)(&kkb_l[tq*72 + kh + j*8]), kkf);
      #pragma unroll
      for (int e=0;e<8;e++){
        int k = kh + j*8 + e;
        kkwT_l[k*136 + tq] = f2b(-kkf[e] * __expf(clip30(wsum_l[k] - WC[tq*65+k])));
      }
    }
  }
  __syncthreads();
  // P4b
  {
    f32x4 accC[8];
    #pragma unroll
    for (int n=0;n<8;n++) accC[n] = ZF4;
    #pragma unroll
    for (int ks=0; ks<2; ++ks){
      s16x8 af = *(const s16x8*)(&ka_l[(wid*16 + fr)*72 + ks*32 + kg*8]);
      #pragma unroll
      for (int n=0;n<8;n++){
        s16x8 bf = *(const s16x8*)(&kkb_l[(n*16 + fr)*72 + ks*32 + kg*8]);
        accC[n] = __builtin_amdgcn_mfma_f32_16x16x32_bf16(af, bf, accC[n], 0,0,0);
      }
    }
    #pragma unroll
    for (int n=0;n<8;n++)
      #pragma unroll
      for (int q=0;q<4;q++){
        int t = wid*16 + kg*4 + q;
        int s = n*16 + fr;
        kkcT[s*136 + t] = f2b((t > s) ? accC[n][q] : 0.f);
      }
  }
  __syncthreads();
  // P5a
  {
    const u16* vs = v_g + base + (size_t)tq*2048 + kh;
    #pragma unroll
    for (int j=0;j<2;j++){
      u16 el[8]; unp16(*(const uint4*)(vs + j*8), el);
      #pragma unroll
      for (int e=0;e<8;e++) vT_l[(kh + j*8 + e)*136 + tq] = el[e];
    }
    #pragma unroll
    for (int j=0;j<2;j++){
      u16 el2[8]; unp16(*(const uint4*)(&ka_l[tq*72 + kh + j*8]), el2);
      #pragma unroll
      for (int e=0;e<8;e++) kaT_l[(kh + j*8 + e)*136 + tq] = el2[e];
    }
  }
  // P5b
  {
    f32x4 accP[8];
    #pragma unroll
    for (int n=0;n<8;n++) accP[n] = ZF4;
    #pragma unroll
    for (int ks=0; ks<4; ++ks){
      s16x8 af = *(const s16x8*)(&Abuf[(wid*16 + fr)*136 + ks*32 + kg*8]);
      #pragma unroll
      for (int n=0;n<8;n++){
        s16x8 bf = *(const s16x8*)(&kkcT[(n*16 + fr)*136 + ks*32 + kg*8]);
        accP[n] = __builtin_amdgcn_mfma_f32_16x16x32_bf16(af, bf, accP[n], 0,0,0);
      }
    }
    #pragma unroll
    for (int n=0;n<8;n++)
      #pragma unroll
      for (int q=0;q<4;q++){
        int t = wid*16 + kg*4 + q;
        int s = n*16 + fr;
        float v = accA[n][q] - ((t >= s) ? accP[n][q] : 0.f);
        Abuf[t*136 + s] = f2b(v);
      }
  }
  __syncthreads();
  // P6
  {
    f32x4 accY[4];
    #pragma unroll
    for (int n=0;n<4;n++) accY[n] = ZF4;
    #pragma unroll
    for (int ks=0; ks<4; ++ks){
      s16x8 af = *(const s16x8*)(&Abuf[(wid*16 + fr)*136 + ks*32 + kg*8]);
      #pragma unroll
      for (int n=0;n<4;n++){
        s16x8 bf = *(const s16x8*)(&vT_l[(n*16 + fr)*136 + ks*32 + kg*8]);
        accY[n] = __builtin_amdgcn_mfma_f32_16x16x32_bf16(af, bf, accY[n], 0,0,0);
      }
    }
    #pragma unroll
    for (int n=0;n<4;n++)
      #pragma unroll
      for (int q=0;q<4;q++){
        int t = wid*16 + kg*4 + q;
        int vd = n*16 + fr;
        y1_g[base + (size_t)t*2048 + vd] = f2b(accY[n][q]);
      }
  }
  // P7
  {
    const int isAB = wid >> 2, mrow = (wid & 3) * 16;
    const u16* Amat = isAB ? kkwT_l : kwT_l;
    const u16* Bmat = isAB ? kaT_l  : vT_l;
    f32x4 acc2[4];
    #pragma unroll
    for (int n=0;n<4;n++) acc2[n] = ZF4;
    #pragma unroll
    for (int ks=0; ks<4; ++ks){
      s16x8 af = *(const s16x8*)(&Amat[(mrow + fr)*136 + ks*32 + kg*8]);
      #pragma unroll
      for (int n=0;n<4;n++){
        s16x8 bf = *(const s16x8*)(&Bmat[(n*16 + fr)*136 + ks*32 + kg*8]);
        acc2[n] = __builtin_amdgcn_mfma_f32_16x16x32_bf16(af, bf, acc2[n], 0,0,0);
      }
    }
    u16* kvp = kvab_g + (size_t)cb*8192 + isAB*4096;
    #pragma unroll
    for (int n=0;n<4;n++)
      #pragma unroll
      for (int q=0;q<4;q++){
        int kd = mrow + kg*4 + q, vd = n*16 + fr;
        if (isAB) kvp[vd*64 + kd] = f2b(acc2[n][q]);
        else      kvp[kd*64 + vd] = f2b(acc2[n][q]);
      }
  }
}

// ---------------------------------------------------------------- WKV phase 2: MFMA state scan, 4-way row split
__global__ __launch_bounds__(256) void wkv2_k(
   const float* __restrict__ state_in, const u16* __restrict__ kvab_g,
   const float* __restrict__ wsA_g, float* __restrict__ sin_g, float* __restrict__ out_state)
{
  __shared__ u16 Sb[16][72];
  __shared__ u16 abT[64][72];
  const int tid = threadIdx.x, lane = tid & 63, wid = tid >> 6;
  const int blk = blockIdx.x;
  const int bh = blk >> 2, rg = blk & 3;
  const int b = bh >> 5, h = bh & 31;
  const int fr = lane & 15, kg = lane >> 4;
  const int lrow = kg*4;
  const int grow = rg*16 + lrow;
  const int vcol = wid*16 + fr;
  const int vrow = tid >> 2, jc = (tid & 3) * 16;

  f32x4 S;
  #pragma unroll
  for (int q=0;q<4;q++)
    S[q] = state_in[(size_t)bh*4096 + (size_t)(grow+q)*64 + vcol];

  uint4 pf_ab0, pf_ab1; u16 pf_kv[4]; float pf_ws;
  {
    int cb = b*32 + h;
    const u16* kvp = kvab_g + (size_t)cb*8192;
    pf_ab0 = *(const uint4*)(kvp + 4096 + vrow*64 + jc);
    pf_ab1 = *(const uint4*)(kvp + 4096 + vrow*64 + jc + 8);
    #pragma unroll
    for (int q=0;q<4;q++) pf_kv[q] = kvp[(grow+q)*64 + vcol];
    pf_ws = wsA_g[(size_t)cb*64 + vcol];
  }

  for (int c=0;c<32;c++){
    int cb = (c*2+b)*32 + h;
    *(uint4*)(&abT[vrow][jc])   = pf_ab0;
    *(uint4*)(&abT[vrow][jc+8]) = pf_ab1;
    #pragma unroll
    for (int q=0;q<4;q++) Sb[lrow+q][vcol] = f2b(S[q]);
    float kvf[4];
    #pragma unroll
    for (int q=0;q<4;q++) kvf[q] = b2f(pf_kv[q]);
    float wsf = pf_ws;
    float* sip = sin_g + (size_t)cb*4096;
    #pragma unroll
    for (int q=0;q<4;q++) sip[(size_t)(grow+q)*64 + vcol] = S[q];
    __syncthreads();
    if (c < 31){
      int cb2 = ((c+1)*2+b)*32 + h;
      const u16* kvp2 = kvab_g + (size_t)cb2*8192;
      pf_ab0 = *(const uint4*)(kvp2 + 4096 + vrow*64 + jc);
      pf_ab1 = *(const uint4*)(kvp2 + 4096 + vrow*64 + jc + 8);
      #pragma unroll
      for (int q=0;q<4;q++) pf_kv[q] = kvp2[(grow+q)*64 + vcol];
      pf_ws = wsA_g[(size_t)cb2*64 + vcol];
    }
    f32x4 acc = ZF4;
    #pragma unroll
    for (int ks=0; ks<2; ++ks){
      s16x8 a  = *(const s16x8*)(&Sb[fr][ks*32 + kg*8]);
      s16x8 bb = *(const s16x8*)(&abT[wid*16 + fr][ks*32 + kg*8]);
      acc = __builtin_amdgcn_mfma_f32_16x16x32_bf16(a, bb, acc, 0,0,0);
    }
    #pragma unroll
    for (int q=0;q<4;q++)
      S[q] = S[q]*wsf + acc[q] + kvf[q];
    __syncthreads();
  }
  #pragma unroll
  for (int q=0;q<4;q++)
    out_state[(size_t)bh*4096 + (size_t)(grow+q)*64 + vcol] = S[q];
}

// ---------------------------------------------------------------- WKV phase 3: MFMA y = y1 + rw@S_in, GroupNorm, *g
__global__ __launch_bounds__(256) void wkv3_k(
   const u16* __restrict__ y1_g, const u16* __restrict__ rw_g,
   const float* __restrict__ sin_g,
   const u16* __restrict__ g_g, const float* __restrict__ gnw, const float* __restrict__ gnb,
   u16* __restrict__ yf_g)
{
  __shared__ u16 rw_l[128][72];
  __shared__ u16 StT[64][72];   // S_in transposed, bf16: StT[vd][k]
  const int tid = threadIdx.x, lane = tid & 63, wid = tid >> 6;
  const int cb = blockIdx.x; int c = cb>>6, b = (cb>>5)&1, h = cb&31;
  size_t base = ((size_t)(b*4096 + c*128))*2048 + h*64;
  const int fr = lane & 15, kg = lane >> 4;
  const float* sip = sin_g + (size_t)cb*4096;
  #pragma unroll
  for (int j=0;j<16;j++){
    int flat = tid*16 + j;                 // k = flat>>6, vd = flat&63
    StT[flat & 63][flat >> 6] = f2b(sip[flat]);
  }
  {
    int t = tid>>1, kh2 = (tid&1)*32;
    const u16* rs = rw_g + base + (size_t)t*2048 + kh2;
    #pragma unroll
    for (int j=0;j<4;j++) *(uint4*)(&rw_l[t][kh2+j*8]) = *(const uint4*)(rs + j*8);
  }
  __syncthreads();
  f32x4 acc[2][4];
  #pragma unroll
  for (int mt=0;mt<2;mt++)
    #pragma unroll
    for (int n=0;n<4;n++) acc[mt][n] = ZF4;
  #pragma unroll
  for (int ks=0; ks<2; ++ks){
    s16x8 a[2];
    #pragma unroll
    for (int mt=0;mt<2;mt++) a[mt] = *(const s16x8*)(&rw_l[wid*32 + mt*16 + fr][ks*32 + kg*8]);
    #pragma unroll
    for (int n=0;n<4;n++){
      s16x8 bb = *(const s16x8*)(&StT[n*16 + fr][ks*32 + kg*8]);
      #pragma unroll
      for (int mt=0;mt<2;mt++)
        acc[mt][n] = __builtin_amdgcn_mfma_f32_16x16x32_bf16(a[mt], bb, acc[mt][n], 0,0,0);
    }
  }
  #pragma unroll
  for (int mt=0;mt<2;mt++){
    float yv[4][4], sum[4], sq[4];
    #pragma unroll
    for (int q=0;q<4;q++){ sum[q]=0.f; sq[q]=0.f; }
    #pragma unroll
    for (int n=0;n<4;n++){
      int vd = n*16 + fr;
      #pragma unroll
      for (int q=0;q<4;q++){
        int t = wid*32 + mt*16 + kg*4 + q;
        float v = acc[mt][n][q] + b2f(y1_g[base + (size_t)t*2048 + vd]);
        yv[n][q] = v; sum[q] += v; sq[q] += v*v;
      }
    }
    #pragma unroll
    for (int q=0;q<4;q++){
      #pragma unroll
      for (int d=1; d<16; d<<=1){
        sum[q] += __shfl_xor(sum[q], d);
        sq[q]  += __shfl_xor(sq[q],  d);
      }
    }
    #pragma unroll
    for (int n=0;n<4;n++){
      int vd = n*16 + fr;
      int ch = h*64 + vd;
      float gw = gnw[ch], gb = gnb[ch];
      #pragma unroll
      for (int q=0;q<4;q++){
        int t = wid*32 + mt*16 + kg*4 + q;
        float mean = sum[q] * (1.f/64.f);
        float var  = sq[q] * (1.f/64.f) - mean*mean;
        float rstd = rsqrtf(fmaxf(var, 0.f) + 6.4e-4f);
        size_t bt = (size_t)(b*4096 + c*128 + t);
        float val = (yv[n][q] - mean)*rstd * gw + gb;
        val *= b2f(g_g[bt*2048 + ch]);
        yf_g[base + (size_t)t*2048 + vd] = f2b(val);
      }
    }
  }
}

// ---------------------------------------------------------------- host
#define O_WTR   0ull
#define O_WTK   8388608ull
#define O_WTV   16777216ull
#define O_WTG   25165824ull
#define O_WTO   33554432ull
#define O_W1T   41943040ull
#define O_W2T   42729472ull
#define O_DW1T  43515904ull
#define O_DW2T  43778048ull
#define O_A1T   44040192ull
#define O_A2T   44433408ull
#define O_XXX   44826624ull
#define O_T2    47972352ull
#define O_T3    49020928ull
#define O_WSA   50593792ull
#define O_XMX   51118080ull       /* xmx -> xw -> r -> S_in(f32) */
#define O_A     84672512ull       /* xk -> v */
#define O_I     118226944ull      /* dxprev -> xa -> iclr */
#define O_R     151781376ull      /* xv -> g */
#define O_K     185335808ull      /* xr -> k -> y1 -> yf */
#define O_V     218890240ull      /* xg -> kvab */
#define WS_NEEDED 252444672ull

extern "C" void kernel_launch(void* const* d_in, const int* in_sizes, int n_in,
                              void* d_out, int out_size, void* d_ws, size_t ws_size,
                              hipStream_t stream)
{
  (void)in_sizes; (void)n_in; (void)out_size;
  if (ws_size < WS_NEEDED) return;
  const float* x     = (const float*)d_in[0];
  const float* shift = (const float*)d_in[1];
  const float* st_in = (const float*)d_in[2];
  const float* maax  = (const float*)d_in[3];
  const float* maas[6] = {(const float*)d_in[4],(const float*)d_in[5],(const float*)d_in[6],
                          (const float*)d_in[7],(const float*)d_in[8],(const float*)d_in[9]};
  const float* w1    = (const float*)d_in[10];
  const float* w2    = (const float*)d_in[11];
  const float* td    = (const float*)d_in[12];
  const float* dw1   = (const float*)d_in[13];
  const float* dw2   = (const float*)d_in[14];
  const float* faaaa = (const float*)d_in[15];
  const float* a0v   = (const float*)d_in[16];
  const float* a1w   = (const float*)d_in[17];
  const float* a2w   = (const float*)d_in[18];
  const float* kkk   = (const float*)d_in[19];
  const float* kka   = (const float*)d_in[20];
  const float* Wr    = (const float*)d_in[21];
  const float* Wk    = (const float*)d_in[22];
  const float* Wv    = (const float*)d_in[23];
  const float* Wg    = (const float*)d_in[24];
  const float* Wo    = (const float*)d_in[25];
  const float* gnw   = (const float*)d_in[26];
  const float* gnb   = (const float*)d_in[27];
  float* out = (float*)d_out;
  char* ws = (char*)d_ws;
  #define WSP(o) ((u16*)(ws + (o)))

  u16 *wtR=WSP(O_WTR), *wtK=WSP(O_WTK), *wtV=WSP(O_WTV), *wtG=WSP(O_WTG), *wtO=WSP(O_WTO);
  u16 *w1t=WSP(O_W1T), *w2t=WSP(O_W2T), *dw1t=WSP(O_DW1T), *dw2t=WSP(O_DW2T), *a1t=WSP(O_A1T), *a2t=WSP(O_A2T);
  u16 *xxx=WSP(O_XXX), *t2b=WSP(O_T2), *t3b=WSP(O_T3);
  u16 *sXMX=WSP(O_XMX), *sA=WSP(O_A), *sI=WSP(O_I), *sR=WSP(O_R), *sK=WSP(O_K), *sV=WSP(O_V);
  u16 *rw = WSP(O_WTR);
  float* sinF = (float*)(ws + O_XMX);
  float* wsA = (float*)(ws + O_WSA);
  float* out_xlast = out + 16777216;
  float* out_state = out + 16781312;

  dim3 tb(32,8);
  transpose5_k<<<dim3(64,64,5), tb, 0, stream>>>(Wr, Wk, Wv, Wg, Wo, wtR, wtK, wtV, wtG, wtO);
  transpose6_k<<<dim3(64,64,6), tb, 0, stream>>>(w1, w2, dw1, dw2, a1w, a2w,
                                                 w1t, w2t, dw1t, dw2t, a1t, a2t);

  prep_k<<<8192, 256, 0, stream>>>(x, shift, maax, sXMX /*xmx*/, sI /*dxp*/, out_xlast);

  // xxx = tanh(xmx @ w1)
  gemm_thin_k<EPI_TANH><<<dim3(128,3), 256, 0, stream>>>(sXMX, 2048, w1t, 2048, xxx, 192, 192, 2048);
  // all 6 token-shift lerps fused
  lerp6_k<<<dim3(64,16), 256, 0, stream>>>(xxx, w2t, x, sI /*dxp*/,
      maas[0], maas[1], maas[2], maas[3], maas[4], maas[5],
      sXMX /*xw*/, sA /*xk*/, sR /*xv*/, sK /*xr*/, sV /*xg*/, sI /*xa*/);
  // t2 = tanh(xw @ dw1) and t3 = xa @ a1 (paired)
  thin2_k<<<dim3(128,2,2), 256, 0, stream>>>(sXMX, dw1t, t2b, 64, sI, a1t, t3b, 96, 2048);
  // iclr = sigmoid(a0 + t3@a2) -> I   (gemm256 path, K=96)
  gemm256_k<EPI_ICLR><<<dim3(32,8), 1024, 0, stream>>>(t3b, a2t, sI, nullptr, 8192, 2048, 96, a0v);
  // big projections: r->XMX, k->K, v->A, g->R
  gemm256_k<EPI_STORE><<<dim3(32,8), 1024, 0, stream>>>(sK, wtR, sXMX, nullptr, 8192, 2048, 2048, nullptr);
  gemm256_k<EPI_STORE><<<dim3(32,8), 1024, 0, stream>>>(sA, wtK, sK, nullptr, 8192, 2048, 2048, nullptr);
  gemm256_k<EPI_STORE><<<dim3(32,8), 1024, 0, stream>>>(sR, wtV, sA, nullptr, 8192, 2048, 2048, nullptr);
  gemm256_k<EPI_SILU><<<dim3(32,8), 1024, 0, stream>>>(sV, wtG, sR, nullptr, 8192, 2048, 2048, nullptr);
  // wkv
  wkv1_k<<<2048, 512, 0, stream>>>(sXMX, sK, sA, sI, t2b, dw2t, td, faaaa, kkk, kka,
                                   sK, rw, sV, wsA);
  wkv2_k<<<256, 256, 0, stream>>>(st_in, sV, wsA, sinF, out_state);
  wkv3_k<<<2048, 256, 0, stream>>>(sK, rw, sinF, sR /*g*/, gnw, gnb, sK /*yf in place*/);
  // out = yf @ W_o  (f32 store)
  gemm256_k<EPI_STORE32><<<dim3(32,8), 1024, 0, stream>>>(sK, wtO, nullptr, out, 8192, 2048, 2048, nullptr);
}